// Round 12
// baseline (39655.731 us; speedup 1.0000x reference)
//
#include <hip/hip_runtime.h>
#include <hip/hip_fp16.h>
#include <hip/hip_cooperative_groups.h>
#include <math.h>

#define NB 128   // batch
#define NT 256   // time
#define NH 512   // hidden
#define NG 2048  // 4H
#define NV 128   // vocab
#define NLW 32   // decode length

__device__ __forceinline__ float sigf(float x){ return 1.0f/(1.0f + expf(-x)); }
__device__ __forceinline__ void fma4(float4& a, float s, float4 w){
  a.x += s*w.x; a.y += s*w.y; a.z += s*w.z; a.w += s*w.w;
}
__device__ __forceinline__ float4 ldh4(const __half* p){
  const __half2* p2 = (const __half2*)p;
  const float2 a = __half22float2(p2[0]);
  const float2 b = __half22float2(p2[1]);
  return make_float4(a.x, a.y, b.x, b.y);
}
__device__ __forceinline__ void ldh8(const __half* p, float4& lo, float4& hi){
  const float4 raw = *(const float4*)p;           // 16 B = 8 halfs, one dwordx4
  const __half2* h2 = (const __half2*)&raw;
  const float2 a = __half22float2(h2[0]);
  const float2 b = __half22float2(h2[1]);
  const float2 c = __half22float2(h2[2]);
  const float2 d = __half22float2(h2[3]);
  lo = make_float4(a.x, a.y, b.x, b.y);
  hi = make_float4(c.x, c.y, d.x, d.y);
}
__device__ __forceinline__ void dot4(float& acc, const float4 a, const float4 b){
  acc += a.x*b.x + a.y*b.y + a.z*b.z + a.w*b.w;
}

// Coherent (agent-scope, L2-bypassing) scalar stores for cross-block state:
// visible at the IF$ coherence point without a release fence (wbl2).
// Readers keep NORMAL cached vector loads; the acquire fence in *_wait
// invalidates stale copies.
__device__ __forceinline__ void stc_f(float* p, float v){
  union { float f; unsigned u; } c; c.f = v;
  __hip_atomic_store((unsigned*)p, c.u, __ATOMIC_RELAXED, __HIP_MEMORY_SCOPE_AGENT);
}
__device__ __forceinline__ void stc_i(int* p, int v){
  __hip_atomic_store(p, v, __ATOMIC_RELAXED, __HIP_MEMORY_SCOPE_AGENT);
}

// ---------------------------------------------------------------------------
// Barriers (R11-validated structure).
// FULL grid barrier (256 blocks): 16 groups x 16, per-block release flags.
// Used by the decoder and ONCE at the encoder phase transition (fenced).
// PER-DIRECTION barrier (128 blocks): 8 groups x 16, per-block flags.
// Used for all in-phase encoder syncs (fence-free arrive; h goes through
// coherent scalar stores). Smaller domain -> smaller straggler set.
// Layouts (ints, 256B-padded lines), zeroed by hipMemsetAsync:
//   full: [g*64] x16 groups, [16*64] root, [1088 + bid*32] flags   (9280)
//   dir:  [g*64] x8  groups, [8*64]  root, [1024 + lid*32] flags   (5120)
// ---------------------------------------------------------------------------
#define FBAR_FLAG0 1088
#define DBAR_FLAG0 1024

__device__ __forceinline__ void full_core(int* bar, int step) {
  const int g = blockIdx.x >> 4;
  const int prev = __hip_atomic_fetch_add(&bar[g*64], 1,
                     __ATOMIC_RELAXED, __HIP_MEMORY_SCOPE_AGENT);
  if (prev == 15) {
    const int r = __hip_atomic_fetch_add(&bar[16*64], 1,
                     __ATOMIC_RELAXED, __HIP_MEMORY_SCOPE_AGENT);
    if (r == 15) {
      #pragma unroll
      for (int i = 0; i < 16; ++i)
        __hip_atomic_store(&bar[i*64], 0, __ATOMIC_RELAXED, __HIP_MEMORY_SCOPE_AGENT);
      __hip_atomic_store(&bar[16*64], 0, __ATOMIC_RELAXED, __HIP_MEMORY_SCOPE_AGENT);
      asm volatile("s_waitcnt vmcnt(0)" ::: "memory");
      #pragma unroll 8
      for (int i = 0; i < 256; ++i)
        __hip_atomic_store(&bar[FBAR_FLAG0 + i*32], step,
                           __ATOMIC_RELAXED, __HIP_MEMORY_SCOPE_AGENT);
    }
  }
}
__device__ __forceinline__ void full_arrive(int* bar, int step) {     // no fence
  __syncthreads();
  if (threadIdx.x == 0) {
    asm volatile("s_waitcnt vmcnt(0)" ::: "memory");
    full_core(bar, step);
  }
}
__device__ __forceinline__ void full_arrive_f(int* bar, int step) {   // fenced
  __syncthreads();
  if (threadIdx.x == 0) {
    __threadfence();                 // release: flush cached y0/etc
    full_core(bar, step);
  }
}
__device__ __forceinline__ void full_wait(int* bar, int step) {
  if (threadIdx.x == 0) {
    int* my = &bar[FBAR_FLAG0 + blockIdx.x*32];
    while (__hip_atomic_load(my, __ATOMIC_RELAXED,
                             __HIP_MEMORY_SCOPE_AGENT) < step)
      __builtin_amdgcn_s_sleep(2);
    __threadfence();                 // acquire
  }
  __syncthreads();
}

__device__ __forceinline__ void dir_arrive(int* dbar, int step) {
  __syncthreads();
  if (threadIdx.x == 0) {
    asm volatile("s_waitcnt vmcnt(0)" ::: "memory");  // coherent stores done
    const int l = blockIdx.x & 127;
    const int g = l >> 4;                              // 8 groups x 16 blocks
    const int prev = __hip_atomic_fetch_add(&dbar[g*64], 1,
                       __ATOMIC_RELAXED, __HIP_MEMORY_SCOPE_AGENT);
    if (prev == 15) {
      const int r = __hip_atomic_fetch_add(&dbar[8*64], 1,
                       __ATOMIC_RELAXED, __HIP_MEMORY_SCOPE_AGENT);
      if (r == 7) {                  // all 128 blocks of this dir arrived
        #pragma unroll
        for (int i = 0; i < 8; ++i)
          __hip_atomic_store(&dbar[i*64], 0, __ATOMIC_RELAXED, __HIP_MEMORY_SCOPE_AGENT);
        __hip_atomic_store(&dbar[8*64], 0, __ATOMIC_RELAXED, __HIP_MEMORY_SCOPE_AGENT);
        asm volatile("s_waitcnt vmcnt(0)" ::: "memory");
        #pragma unroll 8
        for (int i = 0; i < 128; ++i)
          __hip_atomic_store(&dbar[DBAR_FLAG0 + i*32], step,
                             __ATOMIC_RELAXED, __HIP_MEMORY_SCOPE_AGENT);
      }
    }
  }
}
__device__ __forceinline__ void dir_wait(int* dbar, int step) {
  if (threadIdx.x == 0) {
    int* my = &dbar[DBAR_FLAG0 + (blockIdx.x & 127)*32];
    while (__hip_atomic_load(my, __ATOMIC_RELAXED,
                             __HIP_MEMORY_SCOPE_AGENT) < step)
      __builtin_amdgcn_s_sleep(2);
    __threadfence();                 // acquire: drop stale cached h lines
  }
  __syncthreads();
}

// ---------------------------------------------------------------------------
// Persistent cooperative encoder (R11 structure; in-phase syncs are now
// per-direction 128-block barriers; one fenced full barrier at transition).
// ---------------------------------------------------------------------------
struct EncParams {
  const float* x;
  const float* W0ih; const float* W0hh; const float* b0;
  const float* W1ih; const float* W1hh; const float* b1;
  __half* y0; __half* enc;
  float* h0buf; float* h1buf;
  float* c0fin; float* c1fin;
  int*   bar;    // base: dbar0 @0, dbar1 @8192, fbar @16384 (ints)
};

#define W1T_ROW 1542
#define W0T_ROW 518
#define ENC_LDS_FLOATS (16*W1T_ROW + 16*W0T_ROW + 16 + 16 + 128*17)
#define ENC_LDS_BYTES  (ENC_LDS_FLOATS*4)

__device__ __forceinline__ void l1_ih_part(const __half* y0t, const float* W1T,
                                           const float* bias1, int bg2, int cg2,
                                           float acc[2][4]) {
  #pragma unroll
  for (int i = 0; i < 2; ++i)
    #pragma unroll
    for (int j = 0; j < 4; ++j)
      acc[i][j] = bias1[cg2*4 + j];
  const long r0 = (long)(bg2*2+0)*1024, r1 = (long)(bg2*2+1)*1024;
  #pragma unroll 2
  for (int k = 0; k < 1024; k += 8) {
    float4 a0lo, a0hi, a1lo, a1hi;
    ldh8(y0t + r0 + k, a0lo, a0hi);
    ldh8(y0t + r1 + k, a1lo, a1hi);
    #pragma unroll
    for (int j = 0; j < 4; ++j) {
      const float4 wlo = *(const float4*)&W1T[(cg2*4+j)*W1T_ROW + k];
      const float4 whi = *(const float4*)&W1T[(cg2*4+j)*W1T_ROW + k + 4];
      dot4(acc[0][j], a0lo, wlo); dot4(acc[0][j], a0hi, whi);
      dot4(acc[1][j], a1lo, wlo); dot4(acc[1][j], a1hi, whi);
    }
  }
}

__global__ __launch_bounds__(256, 1)
void encoder_kernel(EncParams P) {
  const int tid = threadIdx.x;
  const int bid = blockIdx.x;
  const int dir = bid >> 7;
  const int n0  = (bid & 127) * 4;
  int* dbar = P.bar + dir*8192;
  int* fbar = P.bar + 16384;

  extern __shared__ float lds[];
  float* W1T   = lds;
  float* W0T   = lds + 16*W1T_ROW;
  float* bias0 = W0T + 16*W0T_ROW;
  float* bias1 = bias0 + 16;
  float* gsm   = bias1 + 16;

  {
    const float* Wih1 = P.W1ih + (long)dir*1024*NG;
    const float* Whh1 = P.W1hh + (long)dir*512*NG;
    for (int e = tid; e < 16*1536; e += 256) {
      const int ci = e & 15, kk = e >> 4;
      const int gc = (ci>>2)*NH + n0 + (ci&3);
      W1T[ci*W1T_ROW + kk] = (kk < 1024) ? Wih1[(long)kk*NG + gc]
                                         : Whh1[(long)(kk-1024)*NG + gc];
    }
    const float* Wih0 = P.W0ih + (long)dir*2*NG;
    const float* Whh0 = P.W0hh + (long)dir*512*NG;
    for (int e = tid; e < 16*512; e += 256) {
      const int ci = e & 15, kk = e >> 4;
      const int gc = (ci>>2)*NH + n0 + (ci&3);
      W0T[ci*W0T_ROW + 4 + kk] = Whh0[(long)kk*NG + gc];
    }
    if (tid < 32) {
      const int ci = tid & 15, kk = tid >> 4;
      const int gc = (ci>>2)*NH + n0 + (ci&3);
      W0T[ci*W0T_ROW + kk] = Wih0[(long)kk*NG + gc];
    }
    if (tid < 16) {
      const int gc = (tid>>2)*NH + n0 + (tid&3);
      bias0[tid] = P.b0[(long)dir*NG + gc];
      bias1[tid] = P.b1[(long)dir*NG + gc];
    }
  }
  __syncthreads();

  int dstep = 0;
  float creg0 = 0.f, creg1 = 0.f;

  // phase 1: layer 0 (per-direction barriers)
  {
    const int bg1 = tid >> 3;
    const int cg1 = tid & 7;
    for (int p = 0; p < NT; ++p) {
      const int t = dir ? (NT-1 - p) : p;
      const float* hp = P.h0buf + (long)((p&1)*2 + dir)*65536;
      float acc[4][2];
      #pragma unroll
      for (int i = 0; i < 4; ++i) { acc[i][0] = bias0[cg1*2]; acc[i][1] = bias0[cg1*2+1]; }
      {
        const float w00 = W0T[(cg1*2+0)*W0T_ROW + 0], w01 = W0T[(cg1*2+0)*W0T_ROW + 1];
        const float w10 = W0T[(cg1*2+1)*W0T_ROW + 0], w11 = W0T[(cg1*2+1)*W0T_ROW + 1];
        #pragma unroll
        for (int i = 0; i < 4; ++i) {
          const int b = bg1*4 + i;
          const float x0 = P.x[(long)b*(NT*2) + t*2 + 0];
          const float x1 = P.x[(long)b*(NT*2) + t*2 + 1];
          acc[i][0] += x0*w00 + x1*w01;
          acc[i][1] += x0*w10 + x1*w11;
        }
      }
      #pragma unroll 4
      for (int k = 0; k < NH; k += 4) {
        const float4 w0 = *(const float4*)&W0T[(cg1*2+0)*W0T_ROW + 4 + k];
        const float4 w1 = *(const float4*)&W0T[(cg1*2+1)*W0T_ROW + 4 + k];
        #pragma unroll
        for (int i = 0; i < 4; ++i) {
          const float4 a = *(const float4*)&hp[(long)(bg1*4+i)*NH + k];
          dot4(acc[i][0], a, w0);
          dot4(acc[i][1], a, w1);
        }
      }
      #pragma unroll
      for (int i = 0; i < 4; ++i) {
        gsm[(bg1*4+i)*17 + cg1*2 + 0] = acc[i][0];
        gsm[(bg1*4+i)*17 + cg1*2 + 1] = acc[i][1];
      }
      __syncthreads();
      {
        float* hnext = P.h0buf + (long)(((p+1)&1)*2 + dir)*65536;
        #pragma unroll
        for (int r = 0; r < 2; ++r) {
          const int pi2 = tid + r*256;
          const int b = pi2 >> 2, nl = pi2 & 3;
          const float iv = gsm[b*17 + 0  + nl];
          const float fv = gsm[b*17 + 4  + nl];
          const float gv = gsm[b*17 + 8  + nl];
          const float ov = gsm[b*17 + 12 + nl];
          float cold = r ? creg1 : creg0;
          const float cn = sigf(fv)*cold + sigf(iv)*tanhf(gv);
          const float hn = sigf(ov)*tanhf(cn);
          if (r) creg1 = cn; else creg0 = cn;
          stc_f(&hnext[(long)b*NH + n0 + nl], hn);        // coherent h
          P.y0[((long)t*NB + b)*1024 + dir*NH + n0 + nl] = __float2half_rn(hn);
        }
      }
      if (p < NT-1) { ++dstep; dir_arrive(dbar, dstep); dir_wait(dbar, dstep); }
      else          { full_arrive_f(fbar, 1); full_wait(fbar, 1); }  // transition
    }
    #pragma unroll
    for (int r = 0; r < 2; ++r) {
      const int pi2 = tid + r*256;
      P.c0fin[(long)dir*65536 + (long)(pi2>>2)*NH + n0 + (pi2&3)] = r ? creg1 : creg0;
    }
    creg0 = 0.f; creg1 = 0.f;
  }

  // phase 2: layer 1 (per-direction barriers, barrier-hidden pipeline)
  {
    const int bg2 = tid >> 2;
    const int cg2 = tid & 3;
    float accN[2][4], accC[2][4];
    {
      const int t0i = dir ? (NT-1) : 0;
      l1_ih_part(P.y0 + (long)t0i*NB*1024, W1T, bias1, bg2, cg2, accN);
    }
    for (int p = 0; p < NT; ++p) {
      const int t = dir ? (NT-1 - p) : p;
      #pragma unroll
      for (int i = 0; i < 2; ++i)
        #pragma unroll
        for (int j = 0; j < 4; ++j)
          accC[i][j] = accN[i][j];
      {
        const float* hp = P.h1buf + (long)((p&1)*2 + dir)*65536;
        const long r0 = (long)(bg2*2+0)*NH, r1 = (long)(bg2*2+1)*NH;
        #pragma unroll 4
        for (int k = 0; k < NH; k += 4) {
          const float4 w0 = *(const float4*)&W1T[(cg2*4+0)*W1T_ROW + 1024 + k];
          const float4 w1 = *(const float4*)&W1T[(cg2*4+1)*W1T_ROW + 1024 + k];
          const float4 w2 = *(const float4*)&W1T[(cg2*4+2)*W1T_ROW + 1024 + k];
          const float4 w3 = *(const float4*)&W1T[(cg2*4+3)*W1T_ROW + 1024 + k];
          const float4 a0 = *(const float4*)&hp[r0 + k];
          const float4 a1 = *(const float4*)&hp[r1 + k];
          dot4(accC[0][0], a0, w0); dot4(accC[0][1], a0, w1);
          dot4(accC[0][2], a0, w2); dot4(accC[0][3], a0, w3);
          dot4(accC[1][0], a1, w0); dot4(accC[1][1], a1, w1);
          dot4(accC[1][2], a1, w2); dot4(accC[1][3], a1, w3);
        }
      }
      #pragma unroll
      for (int i = 0; i < 2; ++i)
        #pragma unroll
        for (int j = 0; j < 4; ++j)
          gsm[(bg2*2+i)*17 + cg2*4 + j] = accC[i][j];
      __syncthreads();
      {
        float* hnext = P.h1buf + (long)(((p+1)&1)*2 + dir)*65536;
        #pragma unroll
        for (int r = 0; r < 2; ++r) {
          const int pi2 = tid + r*256;
          const int b = pi2 >> 2, nl = pi2 & 3;
          const float iv = gsm[b*17 + 0  + nl];
          const float fv = gsm[b*17 + 4  + nl];
          const float gv = gsm[b*17 + 8  + nl];
          const float ov = gsm[b*17 + 12 + nl];
          float cold = r ? creg1 : creg0;
          const float cn = sigf(fv)*cold + sigf(iv)*tanhf(gv);
          const float hn = sigf(ov)*tanhf(cn);
          if (r) creg1 = cn; else creg0 = cn;
          stc_f(&hnext[(long)b*NH + n0 + nl], hn);        // coherent h
          P.enc[((long)t*NB + b)*1024 + dir*NH + n0 + nl] = __float2half_rn(hn);
        }
      }
      if (p < NT-1) {
        ++dstep; dir_arrive(dbar, dstep);
        const int tn = dir ? (NT-1 - (p+1)) : (p+1);
        l1_ih_part(P.y0 + (long)tn*NB*1024, W1T, bias1, bg2, cg2, accN);
        dir_wait(dbar, dstep);
      }
    }
    #pragma unroll
    for (int r = 0; r < 2; ++r) {
      const int pi2 = tid + r*256;
      P.c1fin[(long)dir*65536 + (long)(pi2>>2)*NH + n0 + (pi2&3)] = r ? creg1 : creg0;
    }
  }
}

// ---------------------------------------------------------------------------
// Persistent cooperative decoder (identical to R11, validated).
// ---------------------------------------------------------------------------
struct DecParams {
  const float* emb;
  const float* dWih; const float* dWhh; const float* dbv;
  const float* Wq;  const float* bq;
  const float* Wc;  const float* bc;
  const float* Wf;  const float* bf;
  const __half* enc;
  const float* h0e; const float* h1e;
  const float* c0fin; const float* c1fin;
  float* dh0; float* dh1;
  float* query; float* ctx; float* comb;
  int*   tok;
  float* dout;
  int*   bar;
};

#define WD_ROW 1026
#define WQ_ROW 514
#define WC_ROW 1538
#define DEC_LDS_FLOATS (16*WD_ROW + 4*WQ_ROW + 2*WC_ROW + 16 + 4 + 2 + 128*17 \
                        + 1024 + 256 + 64 + 4 + 512 + 128 + 128)
#define DEC_LDS_BYTES  (DEC_LDS_FLOATS*4)

__global__ __launch_bounds__(256, 1)
void decoder_kernel(DecParams P) {
  const int tid = threadIdx.x;
  const int lid = blockIdx.x;
  const int L   = lid >> 7;
  const int n0  = (lid & 127) * 4;
  const int qc0 = lid * 4;
  const int cc0 = lid * 2;
  int* bar = P.bar;

  extern __shared__ float lds[];
  float* WD    = lds;
  float* WqT   = WD + 16*WD_ROW;
  float* WcT   = WqT + 4*WQ_ROW;
  float* biasD = WcT + 2*WC_ROW;
  float* bq4   = biasD + 16;
  float* bc2   = bq4 + 4;
  float* gsm   = bc2 + 2;
  float* qs    = gsm + 128*17;
  float* sc    = qs + 1024;
  float* ps    = sc + 256;
  float* m3    = ps + 64;
  float* cs    = m3 + 4;
  float* vals  = cs + 512;
  int*   idxs  = (int*)(vals + 128);

  {
    const float* Wih = P.dWih + (long)L*512*NG;
    const float* Whh = P.dWhh + (long)L*512*NG;
    for (int e = tid; e < 16*1024; e += 256) {
      const int ci = e & 15, kk = e >> 4;
      const int gc = (ci>>2)*NH + n0 + (ci&3);
      WD[ci*WD_ROW + kk] = (kk < 512) ? Wih[(long)kk*NG + gc]
                                      : Whh[(long)(kk-512)*NG + gc];
    }
    for (int e = tid; e < 4*512; e += 256) {
      const int c = e & 3, kk = e >> 2;
      WqT[c*WQ_ROW + kk] = P.Wq[(long)kk*1024 + qc0 + c];
    }
    for (int e = tid; e < 2*1536; e += 256) {
      const int c = e & 1, kk = e >> 1;
      WcT[c*WC_ROW + kk] = P.Wc[(long)kk*NH + cc0 + c];
    }
    if (tid < 16) biasD[tid] = P.dbv[(long)L*NG + (tid>>2)*NH + n0 + (tid&3)];
    if (tid < 4)  bq4[tid] = P.bq[qc0 + tid];
    if (tid < 2)  bc2[tid] = P.bc[cc0 + tid];
    const int i = lid*256 + tid;
    stc_f(&P.dh0[i], P.h0e[i] + P.h0e[65536 + i]);
    stc_f(&P.dh1[i], P.h1e[i] + P.h1e[65536 + i]);
    if (i < NB) stc_i(&P.tok[i], 1);
  }
  float cregA, cregB;
  {
    const float* cf = L ? P.c1fin : P.c0fin;
    const int b0i = tid >> 2, nl0 = tid & 3;
    cregA = cf[(long)b0i*NH + n0 + nl0] + cf[65536 + (long)b0i*NH + n0 + nl0];
    const int pi2 = tid + 256;
    const int b1i = pi2 >> 2, nl1 = pi2 & 3;
    cregB = cf[(long)b1i*NH + n0 + nl1] + cf[65536 + (long)b1i*NH + n0 + nl1];
  }
  int gstep = 0;
  ++gstep; full_arrive(bar, gstep); full_wait(bar, gstep);

  const int bg = tid >> 3;
  const int cg = tid & 7;

  for (int s = 0; s < NLW; ++s) {
    float* dh0c = P.dh0 + (s&1)*65536;
    float* dh0n = P.dh0 + ((s+1)&1)*65536;
    float* dh1c = P.dh1 + (s&1)*65536;
    float* dh1n = P.dh1 + ((s+1)&1)*65536;

    if (L == 0) {
      float acc[4][2];
      #pragma unroll
      for (int i = 0; i < 4; ++i) { acc[i][0] = biasD[cg*2]; acc[i][1] = biasD[cg*2+1]; }
      int rows[4];
      #pragma unroll
      for (int i = 0; i < 4; ++i) rows[i] = P.tok[bg*4 + i];
      #pragma unroll 4
      for (int k = 0; k < NH; k += 4) {
        const float4 w0 = *(const float4*)&WD[(cg*2+0)*WD_ROW + k];
        const float4 w1 = *(const float4*)&WD[(cg*2+1)*WD_ROW + k];
        #pragma unroll
        for (int i = 0; i < 4; ++i) {
          const float4 a = *(const float4*)&P.emb[(long)rows[i]*NH + k];
          dot4(acc[i][0], a, w0);
          dot4(acc[i][1], a, w1);
        }
      }
      #pragma unroll 4
      for (int k = 0; k < NH; k += 4) {
        const float4 w0 = *(const float4*)&WD[(cg*2+0)*WD_ROW + 512 + k];
        const float4 w1 = *(const float4*)&WD[(cg*2+1)*WD_ROW + 512 + k];
        #pragma unroll
        for (int i = 0; i < 4; ++i) {
          const float4 a = *(const float4*)&dh0c[(long)(bg*4+i)*NH + k];
          dot4(acc[i][0], a, w0);
          dot4(acc[i][1], a, w1);
        }
      }
      #pragma unroll
      for (int i = 0; i < 4; ++i) {
        gsm[(bg*4+i)*17 + cg*2 + 0] = acc[i][0];
        gsm[(bg*4+i)*17 + cg*2 + 1] = acc[i][1];
      }
      __syncthreads();
      #pragma unroll
      for (int r = 0; r < 2; ++r) {
        const int pi2 = tid + r*256;
        const int b = pi2 >> 2, nl = pi2 & 3;
        const float iv = gsm[b*17 + 0  + nl];
        const float fv = gsm[b*17 + 4  + nl];
        const float gv = gsm[b*17 + 8  + nl];
        const float ov = gsm[b*17 + 12 + nl];
        const float cold = r ? cregB : cregA;
        const float cn = sigf(fv)*cold + sigf(iv)*tanhf(gv);
        const float hn = sigf(ov)*tanhf(cn);
        if (r) cregB = cn; else cregA = cn;
        stc_f(&dh0n[(long)b*NH + n0 + nl], hn);
      }
    }
    ++gstep; full_arrive(bar, gstep); full_wait(bar, gstep);

    if (L == 1) {
      float acc[4][2];
      #pragma unroll
      for (int i = 0; i < 4; ++i) { acc[i][0] = biasD[cg*2]; acc[i][1] = biasD[cg*2+1]; }
      #pragma unroll 4
      for (int k = 0; k < NH; k += 4) {
        const float4 w0 = *(const float4*)&WD[(cg*2+0)*WD_ROW + k];
        const float4 w1 = *(const float4*)&WD[(cg*2+1)*WD_ROW + k];
        #pragma unroll
        for (int i = 0; i < 4; ++i) {
          const float4 a = *(const float4*)&dh0n[(long)(bg*4+i)*NH + k];
          dot4(acc[i][0], a, w0);
          dot4(acc[i][1], a, w1);
        }
      }
      #pragma unroll 4
      for (int k = 0; k < NH; k += 4) {
        const float4 w0 = *(const float4*)&WD[(cg*2+0)*WD_ROW + 512 + k];
        const float4 w1 = *(const float4*)&WD[(cg*2+1)*WD_ROW + 512 + k];
        #pragma unroll
        for (int i = 0; i < 4; ++i) {
          const float4 a = *(const float4*)&dh1c[(long)(bg*4+i)*NH + k];
          dot4(acc[i][0], a, w0);
          dot4(acc[i][1], a, w1);
        }
      }
      #pragma unroll
      for (int i = 0; i < 4; ++i) {
        gsm[(bg*4+i)*17 + cg*2 + 0] = acc[i][0];
        gsm[(bg*4+i)*17 + cg*2 + 1] = acc[i][1];
      }
      __syncthreads();
      #pragma unroll
      for (int r = 0; r < 2; ++r) {
        const int pi2 = tid + r*256;
        const int b = pi2 >> 2, nl = pi2 & 3;
        const float iv = gsm[b*17 + 0  + nl];
        const float fv = gsm[b*17 + 4  + nl];
        const float gv = gsm[b*17 + 8  + nl];
        const float ov = gsm[b*17 + 12 + nl];
        const float cold = r ? cregB : cregA;
        const float cn = sigf(fv)*cold + sigf(iv)*tanhf(gv);
        const float hn = sigf(ov)*tanhf(cn);
        if (r) cregB = cn; else cregA = cn;
        stc_f(&dh1n[(long)b*NH + n0 + nl], hn);
      }
    }
    ++gstep; full_arrive(bar, gstep); full_wait(bar, gstep);

    {
      const int b = tid >> 1;
      const int ch = (tid & 1) * 2;
      float a0 = bq4[ch + 0], a1 = bq4[ch + 1];
      const float* hr = dh1n + (long)b*NH;
      #pragma unroll 4
      for (int k = 0; k < NH; k += 4) {
        const float4 a = *(const float4*)&hr[k];
        const float4 w0 = *(const float4*)&WqT[(ch+0)*WQ_ROW + k];
        const float4 w1 = *(const float4*)&WqT[(ch+1)*WQ_ROW + k];
        dot4(a0, a, w0);
        dot4(a1, a, w1);
      }
      stc_f(&P.query[(long)b*1024 + qc0 + ch + 0], a0);
      stc_f(&P.query[(long)b*1024 + qc0 + ch + 1], a1);
    }
    ++gstep; full_arrive(bar, gstep); full_wait(bar, gstep);

    if (lid < NB) {
      const int b = lid;
      for (int i = tid; i < 1024; i += 256) qs[i] = P.query[(long)b*1024 + i];
      if (tid == 0) { m3[0] = -1e30f; m3[1] = 0.f; m3[2] = 0.f; }
      __syncthreads();
      float4 ctx4 = {0,0,0,0};
      for (int c = 0; c < 4; ++c) {
        const int t0 = c*64;
        {
          const int t_l = tid >> 2, part = tid & 3;
          const __half* er = P.enc + ((long)(t0 + t_l)*NB + b)*1024 + part*256;
          const float* qr = qs + part*256;
          float sv = 0.f;
          for (int k = 0; k < 256; k += 4) {
            const float4 e4 = ldh4(er + k);
            const float4 q4 = *(const float4*)(qr + k);
            sv += e4.x*q4.x + e4.y*q4.y + e4.z*q4.z + e4.w*q4.w;
          }
          sv += __shfl_xor(sv, 1);
          sv += __shfl_xor(sv, 2);
          if (part == 0) sc[t0 + t_l] = sv;
        }
        __syncthreads();
        if (tid < 64) {
          float sv = sc[t0 + tid];
          for (int off = 32; off; off >>= 1) sv = fmaxf(sv, __shfl_xor(sv, off));
          if (tid == 0) {
            const float mn = fmaxf(m3[0], sv);
            m3[2] = expf(m3[0] - mn);
            m3[0] = mn;
          }
        }
        __syncthreads();
        const float alpha = m3[2];
        if (tid < 64) {
          float pv = expf(sc[t0 + tid] - m3[0]);
          ps[tid] = pv;
          for (int off = 32; off; off >>= 1) pv += __shfl_xor(pv, off);
          if (tid == 0) m3[1] = m3[1]*alpha + pv;
        }
        __syncthreads();
        ctx4.x *= alpha; ctx4.y *= alpha; ctx4.z *= alpha; ctx4.w *= alpha;
        const __half* ecol = P.enc + ((long)t0*NB + b)*1024 + tid*4;
        for (int t = 0; t < 64; ++t) {
          const float4 e4 = ldh4(ecol + (long)t*(NB*1024));
          fma4(ctx4, ps[t], e4);
        }
        __syncthreads();
      }
      const float linv = 1.0f / m3[1];
      const long cb = (long)b*1024 + tid*4;
      stc_f(&P.ctx[cb+0], ctx4.x*linv); stc_f(&P.ctx[cb+1], ctx4.y*linv);
      stc_f(&P.ctx[cb+2], ctx4.z*linv); stc_f(&P.ctx[cb+3], ctx4.w*linv);
      const float pv = expf(sc[tid] - m3[0]) * linv;
      stc_f(&P.dout[786432L + (long)b*(NT*NLW) + (long)tid*NLW + s], pv);
    }
    ++gstep; full_arrive(bar, gstep); full_wait(bar, gstep);

    {
      const int b = tid >> 1;
      const int col = tid & 1;
      float acc = bc2[col];
      const float* hr = dh1n + (long)b*NH;
      #pragma unroll 4
      for (int k = 0; k < NH; k += 4) {
        const float4 a = *(const float4*)&hr[k];
        const float4 w = *(const float4*)&WcT[col*WC_ROW + k];
        dot4(acc, a, w);
      }
      const float* cr = P.ctx + (long)b*1024;
      #pragma unroll 4
      for (int k = 0; k < 1024; k += 4) {
        const float4 a = *(const float4*)&cr[k];
        const float4 w = *(const float4*)&WcT[col*WC_ROW + 512 + k];
        dot4(acc, a, w);
      }
      stc_f(&P.comb[(long)b*NH + cc0 + col], acc);
    }
    ++gstep; full_arrive(bar, gstep); full_wait(bar, gstep);

    if (lid < NB) {
      const int b = lid;
      for (int i = tid; i < NH; i += 256) cs[i] = P.comb[(long)b*NH + i];
      __syncthreads();
      if (tid < NV) {
        float acc = P.bf[tid];
        for (int k = 0; k < NH; k += 4) {
          const float4 c4 = *(const float4*)&cs[k];
          acc += c4.x*P.Wf[(long)(k+0)*NV + tid];
          acc += c4.y*P.Wf[(long)(k+1)*NV + tid];
          acc += c4.z*P.Wf[(long)(k+2)*NV + tid];
          acc += c4.w*P.Wf[(long)(k+3)*NV + tid];
        }
        stc_f(&P.dout[(long)b*(NLW*NV) + (long)s*NV + tid], acc);
        vals[tid] = acc; idxs[tid] = tid;
      }
      __syncthreads();
      for (int st = 64; st > 0; st >>= 1) {
        if (tid < st) {
          const float v2 = vals[tid+st]; const int i2 = idxs[tid+st];
          if (v2 > vals[tid] || (v2 == vals[tid] && i2 < idxs[tid])) { vals[tid] = v2; idxs[tid] = i2; }
        }
        __syncthreads();
      }
      if (tid == 0) stc_i(&P.tok[b], idxs[0]);
    }
    ++gstep; full_arrive(bar, gstep); full_wait(bar, gstep);
  }

  {
    const int i = lid*256 + tid;
    P.dout[524288L + i]         = P.dh0[i];
    P.dout[524288L + 65536 + i] = P.dh1[i];
    #pragma unroll
    for (int r = 0; r < 2; ++r) {
      const int pi2 = tid + r*256;
      const int b = pi2 >> 2, nl = pi2 & 3;
      P.dout[655360L + (long)L*65536 + (long)b*NH + n0 + nl] = r ? cregB : cregA;
    }
  }
}

// ---------------------------------------------------------------------------
// Fused LSTM gate-GEMM + cell update (fallback paths).
// ---------------------------------------------------------------------------
struct StepDir {
  const void*  A;
  const float* WA;
  const float* Bs;
  const float* WB;
  const float* x2;
  const float* Wx;
  const int*   rowIdxA;
  const float* bias;
  float*  c_io;
  float*  h_out;
  __half* yh_out;
  int sA, KA, sB, KB, sx2, ystride, aHalf;
};
struct StepParams { StepDir d[2]; };

__global__ __launch_bounds__(256)
void lstm_step_kernel(StepParams P) {
  const StepDir p = P.d[blockIdx.z];
  const int tid = threadIdx.x;
  const int nq  = tid & 3;
  const int g   = (tid >> 2) & 3;
  const int bp  = tid >> 4;
  const int bl0 = bp*2;
  const int b0  = blockIdx.y*32 + bl0;
  const int n0  = blockIdx.x*16 + nq*4;
  const int gc  = g*NH + n0;

  float4 acc0 = *(const float4*)(p.bias + gc);
  float4 acc1 = acc0;

  if (p.x2) {
    const float4 w0 = *(const float4*)(p.Wx + gc);
    const float4 w1 = *(const float4*)(p.Wx + NG + gc);
    const float* xr0 = p.x2 + (long)b0     * p.sx2;
    const float* xr1 = p.x2 + (long)(b0+1) * p.sx2;
    fma4(acc0, xr0[0], w0); fma4(acc0, xr0[1], w1);
    fma4(acc1, xr1[0], w0); fma4(acc1, xr1[1], w1);
  }
  if (p.KA > 0) {
    const int r0 = p.rowIdxA ? p.rowIdxA[b0]   : b0;
    const int r1 = p.rowIdxA ? p.rowIdxA[b0+1] : b0+1;
    const float* Wp = p.WA + gc;
    if (p.aHalf) {
      const __half* rA0 = (const __half*)p.A + (long)r0 * p.sA;
      const __half* rA1 = (const __half*)p.A + (long)r1 * p.sA;
      for (int k = 0; k < p.KA; k += 4) {
        const float4 a0 = ldh4(rA0 + k);
        const float4 a1 = ldh4(rA1 + k);
        const float4 w0 = *(const float4*)(Wp + (long)(k+0)*NG);
        const float4 w1 = *(const float4*)(Wp + (long)(k+1)*NG);
        const float4 w2 = *(const float4*)(Wp + (long)(k+2)*NG);
        const float4 w3 = *(const float4*)(Wp + (long)(k+3)*NG);
        fma4(acc0, a0.x, w0); fma4(acc0, a0.y, w1); fma4(acc0, a0.z, w2); fma4(acc0, a0.w, w3);
        fma4(acc1, a1.x, w0); fma4(acc1, a1.y, w1); fma4(acc1, a1.z, w2); fma4(acc1, a1.w, w3);
      }
    } else {
      const float* rA0 = (const float*)p.A + (long)r0 * p.sA;
      const float* rA1 = (const float*)p.A + (long)r1 * p.sA;
      for (int k = 0; k < p.KA; k += 4) {
        const float4 a0 = *(const float4*)(rA0 + k);
        const float4 a1 = *(const float4*)(rA1 + k);
        const float4 w0 = *(const float4*)(Wp + (long)(k+0)*NG);
        const float4 w1 = *(const float4*)(Wp + (long)(k+1)*NG);
        const float4 w2 = *(const float4*)(Wp + (long)(k+2)*NG);
        const float4 w3 = *(const float4*)(Wp + (long)(k+3)*NG);
        fma4(acc0, a0.x, w0); fma4(acc0, a0.y, w1); fma4(acc0, a0.z, w2); fma4(acc0, a0.w, w3);
        fma4(acc1, a1.x, w0); fma4(acc1, a1.y, w1); fma4(acc1, a1.z, w2); fma4(acc1, a1.w, w3);
      }
    }
  }
  {
    const float* rB0 = p.Bs + (long)b0     * p.sB;
    const float* rB1 = p.Bs + (long)(b0+1) * p.sB;
    const float* Wp = p.WB + gc;
    for (int k = 0; k < p.KB; k += 4) {
      const float4 a0 = *(const float4*)(rB0 + k);
      const float4 a1 = *(const float4*)(rB1 + k);
      const float4 w0 = *(const float4*)(Wp + (long)(k+0)*NG);
      const float4 w1 = *(const float4*)(Wp + (long)(k+1)*NG);
      const float4 w2 = *(const float4*)(Wp + (long)(k+2)*NG);
      const float4 w3 = *(const float4*)(Wp + (long)(k+3)*NG);
      fma4(acc0, a0.x, w0); fma4(acc0, a0.y, w1); fma4(acc0, a0.z, w2); fma4(acc0, a0.w, w3);
      fma4(acc1, a1.x, w0); fma4(acc1, a1.y, w1); fma4(acc1, a1.z, w2); fma4(acc1, a1.w, w3);
    }
  }

  __shared__ __align__(16) float gs[32][68];
  {
    float* r0 = &gs[bl0][g*17 + nq*4];
    r0[0]=acc0.x; r0[1]=acc0.y; r0[2]=acc0.z; r0[3]=acc0.w;
    float* r1 = &gs[bl0+1][g*17 + nq*4];
    r1[0]=acc1.x; r1[1]=acc1.y; r1[2]=acc1.z; r1[3]=acc1.w;
  }
  __syncthreads();
  for (int pi = tid; pi < 512; pi += 256) {
    const int b_l = pi >> 4, n_l = pi & 15;
    const float iv = gs[b_l][0*17 + n_l];
    const float fv = gs[b_l][1*17 + n_l];
    const float gv = gs[b_l][2*17 + n_l];
    const float ov = gs[b_l][3*17 + n_l];
    const int bg = blockIdx.y*32 + b_l;
    const long idx = (long)bg*NH + blockIdx.x*16 + n_l;
    const float c_old = p.c_io[idx];
    const float cn = sigf(fv)*c_old + sigf(iv)*tanhf(gv);
    const float hn = sigf(ov)*tanhf(cn);
    p.c_io[idx]  = cn;
    p.h_out[idx] = hn;
    if (p.yh_out)
      p.yh_out[(long)bg*p.ystride + blockIdx.x*16 + n_l] = __float2half_rn(hn);
  }
}

// ---------------------------------------------------------------------------
struct LinParams {
  const float* A; const float* Bs; const float* W; const float* bias;
  float* out;
  int sA, KA, sB, KB, N;
};

__global__ __launch_bounds__(256)
void linear2_kernel(LinParams p) {
  __shared__ __align__(16) float As[64][36];
  const int tid = threadIdx.x;
  const int jl = tid & 63;
  const int j = blockIdx.x*64 + jl;
  const int bo = (tid >> 6)*8;
  const int bbase = blockIdx.y*32;
  float acc[8] = {0,0,0,0,0,0,0,0};
  for (int src = 0; src < 2; ++src) {
    const float* A = src ? p.Bs : p.A;
    const int sA   = src ? p.sB : p.sA;
    const int K    = src ? p.KB : p.KA;
    const float* W = src ? (p.W + (long)p.KA*p.N) : p.W;
    if (!A || K <= 0) continue;
    for (int k0 = 0; k0 < K; k0 += 64) {
      __syncthreads();
      for (int e = tid; e < 32*64; e += 256) {
        const int bl = e >> 6, kk = e & 63;
        As[kk][bl] = A[(long)(bbase+bl)*sA + k0 + kk];
      }
      __syncthreads();
      const float* Wp = W + (long)k0*p.N + j;
      for (int k = 0; k < 64; ++k) {
        const float wv = Wp[(long)k*p.N];
        const float4 aA = *(const float4*)&As[k][bo];
        const float4 aB = *(const float4*)&As[k][bo+4];
        acc[0] += aA.x*wv; acc[1] += aA.y*wv; acc[2] += aA.z*wv; acc[3] += aA.w*wv;
        acc[4] += aB.x*wv; acc[5] += aB.y*wv; acc[6] += aB.z*wv; acc[7] += aB.w*wv;
      }
    }
  }
  const float bv = p.bias ? p.bias[j] : 0.f;
  for (int i = 0; i < 8; ++i)
    p.out[(long)(bbase + bo + i)*p.N + j] = acc[i] + bv;
}

// ---------------------------------------------------------------------------
__global__ __launch_bounds__(256)
void attn_kernel(const float* __restrict__ query, const __half* __restrict__ enc,
                 float* __restrict__ context, float* __restrict__ attn_out, int step) {
  const int b = blockIdx.x;
  const int tid = threadIdx.x;
  __shared__ __align__(16) float qs[1024];
  __shared__ float sc[256];
  __shared__ float ps[64];
  __shared__ float msh, lsh, ash;
  for (int i = tid; i < 1024; i += 256) qs[i] = query[(long)b*1024 + i];
  if (tid == 0) { msh = -1e30f; lsh = 0.f; ash = 0.f; }
  __syncthreads();
  float4 ctx = {0,0,0,0};
  for (int c = 0; c < 4; ++c) {
    const int t0 = c*64;
    {
      const int t_l = tid >> 2, part = tid & 3;
      const __half* er = enc + ((long)(t0 + t_l)*NB + b)*1024 + part*256;
      const float* qr = qs + part*256;
      float sv = 0.f;
      for (int k = 0; k < 256; k += 4) {
        const float4 e4 = ldh4(er + k);
        const float4 q4 = *(const float4*)(qr + k);
        sv += e4.x*q4.x + e4.y*q4.y + e4.z*q4.z + e4.w*q4.w;
      }
      sv += __shfl_xor(sv, 1);
      sv += __shfl_xor(sv, 2);
      if (part == 0) sc[t0 + t_l] = sv;
    }
    __syncthreads();
    if (tid < 64) {
      float sv = sc[t0 + tid];
      for (int off = 32; off; off >>= 1) sv = fmaxf(sv, __shfl_xor(sv, off));
      if (tid == 0) {
        const float mn = fmaxf(msh, sv);
        ash = expf(msh - mn);
        msh = mn;
      }
    }
    __syncthreads();
    const float alpha = ash;
    if (tid < 64) {
      float pv = expf(sc[t0 + tid] - msh);
      ps[tid] = pv;
      for (int off = 32; off; off >>= 1) pv += __shfl_xor(pv, off);
      if (tid == 0) lsh = lsh*alpha + pv;
    }
    __syncthreads();
    ctx.x *= alpha; ctx.y *= alpha; ctx.z *= alpha; ctx.w *= alpha;
    const __half* ecol = enc + ((long)t0*NB + b)*1024 + tid*4;
    for (int t = 0; t < 64; ++t) {
      const float4 e4 = ldh4(ecol + (long)t*(NB*1024));
      fma4(ctx, ps[t], e4);
    }
    __syncthreads();
  }
  const float linv = 1.0f / lsh;
  const long cb = (long)b*1024 + tid*4;
  context[cb+0] = ctx.x*linv; context[cb+1] = ctx.y*linv;
  context[cb+2] = ctx.z*linv; context[cb+3] = ctx.w*linv;
  const float pv = expf(sc[tid] - msh) * linv;
  attn_out[(long)b*(NT*NLW) + (long)tid*NLW + step] = pv;
}

// ---------------------------------------------------------------------------
__global__ __launch_bounds__(128)
void logits_kernel(const float* __restrict__ comb, const float* __restrict__ Wf,
                   const float* __restrict__ bfv, float* __restrict__ out,
                   int sOut, int* __restrict__ tok) {
  const int b = blockIdx.x;
  const int v = threadIdx.x;
  __shared__ __align__(16) float cs[512];
  __shared__ float vals[128];
  __shared__ int idxs[128];
  for (int i = v; i < 512; i += 128) cs[i] = comb[(long)b*512 + i];
  __syncthreads();
  float acc = bfv[v];
  for (int k = 0; k < 512; k += 4) {
    const float4 c4 = *(const float4*)&cs[k];
    acc += c4.x*Wf[(long)(k+0)*NV + v];
    acc += c4.y*Wf[(long)(k+1)*NV + v];
    acc += c4.z*Wf[(long)(k+2)*NV + v];
    acc += c4.w*Wf[(long)(k+3)*NV + v];
  }
  out[(long)b*sOut + v] = acc;
  vals[v] = acc; idxs[v] = v;
  __syncthreads();
  for (int s = 64; s > 0; s >>= 1) {
    if (v < s) {
      const float v2 = vals[v+s]; const int i2 = idxs[v+s];
      if (v2 > vals[v] || (v2 == vals[v] && i2 < idxs[v])) { vals[v] = v2; idxs[v] = i2; }
    }
    __syncthreads();
  }
  if (v == 0) tok[b] = idxs[0];
}

// ---------------------------------------------------------------------------
__global__ void init_dec_kernel(const float* h00, const float* h01,
                                const float* c00, const float* c01,
                                const float* h10, const float* h11,
                                const float* c10, const float* c11,
                                float* dh0, float* dh1, float* dc0, float* dc1,
                                int* tok) {
  const int i = blockIdx.x*256 + threadIdx.x;
  dh0[i] = h00[i] + h01[i];
  dc0[i] = c00[i] + c01[i];
  dh1[i] = h10[i] + h11[i];
  dc1[i] = c10[i] + c11[i];
  if (i < NB) tok[i] = 1;
}

__global__ void final_copy_kernel(const float* dh0, const float* dh1,
                                  const float* dc0, const float* dc1,
                                  float* out_h, float* out_c) {
  const int i = blockIdx.x*256 + threadIdx.x;
  out_h[i] = dh0[i]; out_h[65536 + i] = dh1[i];
  out_c[i] = dc0[i]; out_c[65536 + i] = dc1[i];
}

// ---------------------------------------------------------------------------
extern "C" void kernel_launch(void* const* d_in, const int* in_sizes, int n_in,
                              void* d_out_v, int out_size, void* d_ws, size_t ws_size,
                              hipStream_t stream) {
  (void)in_sizes; (void)n_in; (void)out_size;
  const float* x    = (const float*)d_in[0];
  const float* W0ih = (const float*)d_in[1];
  const float* W0hh = (const float*)d_in[2];
  const float* b0v  = (const float*)d_in[3];
  const float* W1ih = (const float*)d_in[4];
  const float* W1hh = (const float*)d_in[5];
  const float* b1v  = (const float*)d_in[6];
  const float* dWih = (const float*)d_in[7];
  const float* dWhh = (const float*)d_in[8];
  const float* dbv  = (const float*)d_in[9];
  const float* emb  = (const float*)d_in[10];
  const float* Wq   = (const float*)d_in[11];
  const float* bq   = (const float*)d_in[12];
  const float* Wc   = (const float*)d_in[13];
  const float* bc   = (const float*)d_in[14];
  const float* Wf   = (const float*)d_in[15];
  const float* bfv  = (const float*)d_in[16];

  // ---- workspace layout (float slots) ----
  // encoder bar: dbar0 @0, dbar1 @8192, fbar @16384 (9280) -> 26624 ints
  // decoder bar: 9280 ints -> pad; total bar region 40960 ints
  const long Y0_SLOTS  = 16777216L;
  const long ENC_SLOTS = 16777216L;
  const long BAR_SLOTS = 40960L;
  const long ST_SZ     = 786432L + BAR_SLOTS;
  const long DEC_SZ    = 655488L;
  const long NEEDED    = Y0_SLOTS + ENC_SLOTS + ST_SZ + DEC_SZ;
  if (ws_size < (size_t)NEEDED*4) return;

  float*  ws    = (float*)d_ws;
  __half* y0h   = (__half*)ws;
  __half* ench  = (__half*)(ws + Y0_SLOTS);
  float*  st    = ws + Y0_SLOTS + ENC_SLOTS;
  float*  h0buf = st;
  float*  h1buf = st + 262144;
  float*  c0fin = st + 524288;
  float*  c1fin = st + 655360;
  int*    barE  = (int*)(st + 786432);       // 26624 ints used
  int*    barD  = barE + 28672;              // decoder full barrier
  float*  dec   = st + ST_SZ;
  float* ddh0  = dec + 0;
  float* ddh1  = dec + 131072;
  float* dcomb = dec + 262144;
  float* query = dec + 393216;
  float* ctx   = dec + 524288;
  int*   tok   = (int*)(dec + 655360);
  float* dh[2][2] = {{dec+0, dec+65536}, {dec+131072, dec+196608}};
  float* dc[2]    =  {dec+262144, dec+327680};
  float* comb  = query;
  float* dout  = (float*)d_out_v;

  hipMemsetAsync(st, 0, ST_SZ*4, stream);

  EncParams EP;
  EP.x = x; EP.W0ih = W0ih; EP.W0hh = W0hh; EP.b0 = b0v;
  EP.W1ih = W1ih; EP.W1hh = W1hh; EP.b1 = b1v;
  EP.y0 = y0h; EP.enc = ench;
  EP.h0buf = h0buf; EP.h1buf = h1buf; EP.c0fin = c0fin; EP.c1fin = c1fin;
  EP.bar = barE;

  static int attrDone = 0;
  if (!attrDone) {
    (void)hipFuncSetAttribute(reinterpret_cast<const void*>(encoder_kernel),
                              hipFuncAttributeMaxDynamicSharedMemorySize,
                              ENC_LDS_BYTES);
    (void)hipFuncSetAttribute(reinterpret_cast<const void*>(decoder_kernel),
                              hipFuncAttributeMaxDynamicSharedMemorySize,
                              DEC_LDS_BYTES);
    attrDone = 1;
  }
  void* eargs[] = { (void*)&EP };
  hipError_t cerr = hipLaunchCooperativeKernel(
      reinterpret_cast<const void*>(encoder_kernel),
      dim3(256), dim3(256), eargs, (unsigned int)ENC_LDS_BYTES, stream);

  if (cerr != hipSuccess) {
    for (int p = 0; p < NT; ++p) {
      StepParams SP{};
      for (int d = 0; d < 2; ++d) {
        const int t = d ? (NT-1-p) : p;
        StepDir& q = SP.d[d];
        q.A = nullptr; q.WA = nullptr; q.sA = 0; q.KA = 0; q.aHalf = 0;
        q.Bs = h0buf + (long)((p&1)*2 + d)*65536; q.sB = NH; q.KB = NH;
        q.WB = W0hh + (long)d*NH*NG;
        q.x2 = x + (long)t*2; q.sx2 = NT*2; q.Wx = W0ih + (long)d*2*NG;
        q.rowIdxA = nullptr; q.bias = b0v + (long)d*NG;
        q.c_io = c0fin + (long)d*65536;
        q.h_out = h0buf + (long)(((p+1)&1)*2 + d)*65536;
        q.yh_out = y0h + (long)t*(NB*1024) + d*NH; q.ystride = 1024;
      }
      lstm_step_kernel<<<dim3(32,4,2), 256, 0, stream>>>(SP);
    }
    for (int p = 0; p < NT; ++p) {
      StepParams SP{};
      for (int d = 0; d < 2; ++d) {
        const int t = d ? (NT-1-p) : p;
        StepDir& q = SP.d[d];
        q.A = y0h + (long)t*(NB*1024); q.aHalf = 1; q.sA = 1024; q.KA = 2*NH;
        q.WA = W1ih + (long)d*(2*NH)*NG;
        q.Bs = h1buf + (long)((p&1)*2 + d)*65536; q.sB = NH; q.KB = NH;
        q.WB = W1hh + (long)d*NH*NG;
        q.x2 = nullptr; q.sx2 = 0; q.Wx = nullptr;
        q.rowIdxA = nullptr; q.bias = b1v + (long)d*NG;
        q.c_io = c1fin + (long)d*65536;
        q.h_out = h1buf + (long)(((p+1)&1)*2 + d)*65536;
        q.yh_out = ench + (long)t*(NB*1024) + d*NH; q.ystride = 1024;
      }
      lstm_step_kernel<<<dim3(32,4,2), 256, 0, stream>>>(SP);
    }
  }

  DecParams DP;
  DP.emb = emb; DP.dWih = dWih; DP.dWhh = dWhh; DP.dbv = dbv;
  DP.Wq = Wq; DP.bq = bq; DP.Wc = Wc; DP.bc = bc; DP.Wf = Wf; DP.bf = bfv;
  DP.enc = ench;
  DP.h0e = h0buf; DP.h1e = h1buf;
  DP.c0fin = c0fin; DP.c1fin = c1fin;
  DP.dh0 = ddh0; DP.dh1 = ddh1;
  DP.query = query; DP.ctx = ctx; DP.comb = dcomb;
  DP.tok = tok; DP.dout = dout; DP.bar = barD;

  void* dargs[] = { (void*)&DP };
  hipError_t derr = hipLaunchCooperativeKernel(
      reinterpret_cast<const void*>(decoder_kernel),
      dim3(256), dim3(256), dargs, (unsigned int)DEC_LDS_BYTES, stream);

  if (derr != hipSuccess) {
    init_dec_kernel<<<256, 256, 0, stream>>>(h0buf, h0buf+65536, c0fin, c0fin+65536,
                                             h1buf, h1buf+65536, c1fin, c1fin+65536,
                                             dh[0][0], dh[1][0], dc[0], dc[1], tok);
    for (int s = 0; s < NLW; ++s) {
      const int si = s&1, so = (s+1)&1;
      {
        StepParams SP{};
        StepDir& q = SP.d[0];
        q.A = emb; q.sA = NH; q.KA = NH; q.aHalf = 0; q.WA = dWih;
        q.Bs = dh[0][si]; q.sB = NH; q.KB = NH; q.WB = dWhh;
        q.x2 = nullptr; q.sx2 = 0; q.Wx = nullptr;
        q.rowIdxA = tok;
        q.bias = dbv;
        q.c_io = dc[0]; q.h_out = dh[0][so];
        q.yh_out = nullptr; q.ystride = 0;
        lstm_step_kernel<<<dim3(32,4,1), 256, 0, stream>>>(SP);
      }
      {
        StepParams SP{};
        StepDir& q = SP.d[0];
        q.A = dh[0][so]; q.sA = NH; q.KA = NH; q.aHalf = 0; q.WA = dWih + (long)NH*NG;
        q.Bs = dh[1][si]; q.sB = NH; q.KB = NH; q.WB = dWhh + (long)NH*NG;
        q.x2 = nullptr; q.sx2 = 0; q.Wx = nullptr;
        q.rowIdxA = nullptr;
        q.bias = dbv + NG;
        q.c_io = dc[1]; q.h_out = dh[1][so];
        q.yh_out = nullptr; q.ystride = 0;
        lstm_step_kernel<<<dim3(32,4,1), 256, 0, stream>>>(SP);
      }
      {
        LinParams LP{ dh[1][so], nullptr, Wq, bq, query, NH, NH, 0, 0, 2*NH };
        linear2_kernel<<<dim3(16,4), 256, 0, stream>>>(LP);
      }
      attn_kernel<<<128, 256, 0, stream>>>(query, ench, ctx, dout + 786432L, s);
      {
        LinParams LP{ dh[1][so], ctx, Wc, bc, comb, NH, NH, 2*NH, 2*NH, NH };
        linear2_kernel<<<dim3(8,4), 256, 0, stream>>>(LP);
      }
      logits_kernel<<<128, 128, 0, stream>>>(comb, Wf, bfv, dout + (long)s*NV,
                                             NLW*NV, tok);
    }
    final_copy_kernel<<<256, 256, 0, stream>>>(dh[0][0], dh[1][0], dc[0], dc[1],
                                               dout + 524288L, dout + 655360L);
  }
}

// Round 13
// 38953.836 us; speedup vs baseline: 1.0180x; 1.0180x over previous
//
#include <hip/hip_runtime.h>
#include <hip/hip_fp16.h>
#include <hip/hip_cooperative_groups.h>
#include <math.h>

#define NB 128   // batch
#define NT 256   // time
#define NH 512   // hidden
#define NG 2048  // 4H
#define NV 128   // vocab
#define NLW 32   // decode length

__device__ __forceinline__ float sigf(float x){ return 1.0f/(1.0f + expf(-x)); }
__device__ __forceinline__ void fma4(float4& a, float s, float4 w){
  a.x += s*w.x; a.y += s*w.y; a.z += s*w.z; a.w += s*w.w;
}
__device__ __forceinline__ float4 ldh4(const __half* p){
  const __half2* p2 = (const __half2*)p;
  const float2 a = __half22float2(p2[0]);
  const float2 b = __half22float2(p2[1]);
  return make_float4(a.x, a.y, b.x, b.y);
}
__device__ __forceinline__ void ldh8(const __half* p, float4& lo, float4& hi){
  const float4 raw = *(const float4*)p;           // 16 B = 8 halfs, one dwordx4
  const __half2* h2 = (const __half2*)&raw;
  const float2 a = __half22float2(h2[0]);
  const float2 b = __half22float2(h2[1]);
  const float2 c = __half22float2(h2[2]);
  const float2 d = __half22float2(h2[3]);
  lo = make_float4(a.x, a.y, b.x, b.y);
  hi = make_float4(c.x, c.y, d.x, d.y);
}
__device__ __forceinline__ void dot4(float& acc, const float4 a, const float4 b){
  acc += a.x*b.x + a.y*b.y + a.z*b.z + a.w*b.w;
}

// Coherent (agent-scope, L2-bypassing) scalar stores for cross-block state:
// visible at the IF$ coherence point without a release fence (wbl2).
// Readers keep NORMAL cached vector loads; the acquire fence in *_wait
// invalidates stale copies.
__device__ __forceinline__ void stc_f(float* p, float v){
  union { float f; unsigned u; } c; c.f = v;
  __hip_atomic_store((unsigned*)p, c.u, __ATOMIC_RELAXED, __HIP_MEMORY_SCOPE_AGENT);
}
__device__ __forceinline__ void stc_i(int* p, int v){
  __hip_atomic_store(p, v, __ATOMIC_RELAXED, __HIP_MEMORY_SCOPE_AGENT);
}

// ---------------------------------------------------------------------------
// Barriers (R11/R12-validated structure).
// FULL grid barrier (256 blocks): 16 groups x 16, per-block release flags.
// PER-DIRECTION barrier (128 blocks): 8 groups x 16, per-block flags.
// ---------------------------------------------------------------------------
#define FBAR_FLAG0 1088
#define DBAR_FLAG0 1024

__device__ __forceinline__ void full_core(int* bar, int step) {
  const int g = blockIdx.x >> 4;
  const int prev = __hip_atomic_fetch_add(&bar[g*64], 1,
                     __ATOMIC_RELAXED, __HIP_MEMORY_SCOPE_AGENT);
  if (prev == 15) {
    const int r = __hip_atomic_fetch_add(&bar[16*64], 1,
                     __ATOMIC_RELAXED, __HIP_MEMORY_SCOPE_AGENT);
    if (r == 15) {
      #pragma unroll
      for (int i = 0; i < 16; ++i)
        __hip_atomic_store(&bar[i*64], 0, __ATOMIC_RELAXED, __HIP_MEMORY_SCOPE_AGENT);
      __hip_atomic_store(&bar[16*64], 0, __ATOMIC_RELAXED, __HIP_MEMORY_SCOPE_AGENT);
      asm volatile("s_waitcnt vmcnt(0)" ::: "memory");
      #pragma unroll 8
      for (int i = 0; i < 256; ++i)
        __hip_atomic_store(&bar[FBAR_FLAG0 + i*32], step,
                           __ATOMIC_RELAXED, __HIP_MEMORY_SCOPE_AGENT);
    }
  }
}
__device__ __forceinline__ void full_arrive(int* bar, int step) {     // no fence
  __syncthreads();
  if (threadIdx.x == 0) {
    asm volatile("s_waitcnt vmcnt(0)" ::: "memory");
    full_core(bar, step);
  }
}
__device__ __forceinline__ void full_arrive_f(int* bar, int step) {   // fenced
  __syncthreads();
  if (threadIdx.x == 0) {
    __threadfence();                 // release: flush cached y0/etc
    full_core(bar, step);
  }
}
__device__ __forceinline__ void full_wait(int* bar, int step) {
  if (threadIdx.x == 0) {
    int* my = &bar[FBAR_FLAG0 + blockIdx.x*32];
    while (__hip_atomic_load(my, __ATOMIC_RELAXED,
                             __HIP_MEMORY_SCOPE_AGENT) < step)
      __builtin_amdgcn_s_sleep(2);
    __threadfence();                 // acquire
  }
  __syncthreads();
}

__device__ __forceinline__ void dir_arrive(int* dbar, int step) {
  __syncthreads();
  if (threadIdx.x == 0) {
    asm volatile("s_waitcnt vmcnt(0)" ::: "memory");  // coherent stores done
    const int l = blockIdx.x & 127;
    const int g = l >> 4;                              // 8 groups x 16 blocks
    const int prev = __hip_atomic_fetch_add(&dbar[g*64], 1,
                       __ATOMIC_RELAXED, __HIP_MEMORY_SCOPE_AGENT);
    if (prev == 15) {
      const int r = __hip_atomic_fetch_add(&dbar[8*64], 1,
                       __ATOMIC_RELAXED, __HIP_MEMORY_SCOPE_AGENT);
      if (r == 7) {                  // all 128 blocks of this dir arrived
        #pragma unroll
        for (int i = 0; i < 8; ++i)
          __hip_atomic_store(&dbar[i*64], 0, __ATOMIC_RELAXED, __HIP_MEMORY_SCOPE_AGENT);
        __hip_atomic_store(&dbar[8*64], 0, __ATOMIC_RELAXED, __HIP_MEMORY_SCOPE_AGENT);
        asm volatile("s_waitcnt vmcnt(0)" ::: "memory");
        #pragma unroll 8
        for (int i = 0; i < 128; ++i)
          __hip_atomic_store(&dbar[DBAR_FLAG0 + i*32], step,
                             __ATOMIC_RELAXED, __HIP_MEMORY_SCOPE_AGENT);
      }
    }
  }
}
__device__ __forceinline__ void dir_wait(int* dbar, int step) {
  if (threadIdx.x == 0) {
    int* my = &dbar[DBAR_FLAG0 + (blockIdx.x & 127)*32];
    while (__hip_atomic_load(my, __ATOMIC_RELAXED,
                             __HIP_MEMORY_SCOPE_AGENT) < step)
      __builtin_amdgcn_s_sleep(2);
    __threadfence();                 // acquire: drop stale cached h lines
  }
  __syncthreads();
}

// ---------------------------------------------------------------------------
// Persistent cooperative encoder (R12 structure, unchanged).
// ---------------------------------------------------------------------------
struct EncParams {
  const float* x;
  const float* W0ih; const float* W0hh; const float* b0;
  const float* W1ih; const float* W1hh; const float* b1;
  __half* y0; __half* enc;
  float* h0buf; float* h1buf;
  float* c0fin; float* c1fin;
  int*   bar;    // base: dbar0 @0, dbar1 @8192, fbar @16384 (ints)
};

#define W1T_ROW 1542
#define W0T_ROW 518
#define ENC_LDS_FLOATS (16*W1T_ROW + 16*W0T_ROW + 16 + 16 + 128*17)
#define ENC_LDS_BYTES  (ENC_LDS_FLOATS*4)

__device__ __forceinline__ void l1_ih_part(const __half* y0t, const float* W1T,
                                           const float* bias1, int bg2, int cg2,
                                           float acc[2][4]) {
  #pragma unroll
  for (int i = 0; i < 2; ++i)
    #pragma unroll
    for (int j = 0; j < 4; ++j)
      acc[i][j] = bias1[cg2*4 + j];
  const long r0 = (long)(bg2*2+0)*1024, r1 = (long)(bg2*2+1)*1024;
  #pragma unroll 2
  for (int k = 0; k < 1024; k += 8) {
    float4 a0lo, a0hi, a1lo, a1hi;
    ldh8(y0t + r0 + k, a0lo, a0hi);
    ldh8(y0t + r1 + k, a1lo, a1hi);
    #pragma unroll
    for (int j = 0; j < 4; ++j) {
      const float4 wlo = *(const float4*)&W1T[(cg2*4+j)*W1T_ROW + k];
      const float4 whi = *(const float4*)&W1T[(cg2*4+j)*W1T_ROW + k + 4];
      dot4(acc[0][j], a0lo, wlo); dot4(acc[0][j], a0hi, whi);
      dot4(acc[1][j], a1lo, wlo); dot4(acc[1][j], a1hi, whi);
    }
  }
}

__global__ __launch_bounds__(256, 1)
void encoder_kernel(EncParams P) {
  const int tid = threadIdx.x;
  const int bid = blockIdx.x;
  const int dir = bid >> 7;
  const int n0  = (bid & 127) * 4;
  int* dbar = P.bar + dir*8192;
  int* fbar = P.bar + 16384;

  extern __shared__ float lds[];
  float* W1T   = lds;
  float* W0T   = lds + 16*W1T_ROW;
  float* bias0 = W0T + 16*W0T_ROW;
  float* bias1 = bias0 + 16;
  float* gsm   = bias1 + 16;

  {
    const float* Wih1 = P.W1ih + (long)dir*1024*NG;
    const float* Whh1 = P.W1hh + (long)dir*512*NG;
    for (int e = tid; e < 16*1536; e += 256) {
      const int ci = e & 15, kk = e >> 4;
      const int gc = (ci>>2)*NH + n0 + (ci&3);
      W1T[ci*W1T_ROW + kk] = (kk < 1024) ? Wih1[(long)kk*NG + gc]
                                         : Whh1[(long)(kk-1024)*NG + gc];
    }
    const float* Wih0 = P.W0ih + (long)dir*2*NG;
    const float* Whh0 = P.W0hh + (long)dir*512*NG;
    for (int e = tid; e < 16*512; e += 256) {
      const int ci = e & 15, kk = e >> 4;
      const int gc = (ci>>2)*NH + n0 + (ci&3);
      W0T[ci*W0T_ROW + 4 + kk] = Whh0[(long)kk*NG + gc];
    }
    if (tid < 32) {
      const int ci = tid & 15, kk = tid >> 4;
      const int gc = (ci>>2)*NH + n0 + (ci&3);
      W0T[ci*W0T_ROW + kk] = Wih0[(long)kk*NG + gc];
    }
    if (tid < 16) {
      const int gc = (tid>>2)*NH + n0 + (tid&3);
      bias0[tid] = P.b0[(long)dir*NG + gc];
      bias1[tid] = P.b1[(long)dir*NG + gc];
    }
  }
  __syncthreads();

  int dstep = 0;
  float creg0 = 0.f, creg1 = 0.f;

  // phase 1: layer 0 (per-direction barriers)
  {
    const int bg1 = tid >> 3;
    const int cg1 = tid & 7;
    for (int p = 0; p < NT; ++p) {
      const int t = dir ? (NT-1 - p) : p;
      const float* hp = P.h0buf + (long)((p&1)*2 + dir)*65536;
      float acc[4][2];
      #pragma unroll
      for (int i = 0; i < 4; ++i) { acc[i][0] = bias0[cg1*2]; acc[i][1] = bias0[cg1*2+1]; }
      {
        const float w00 = W0T[(cg1*2+0)*W0T_ROW + 0], w01 = W0T[(cg1*2+0)*W0T_ROW + 1];
        const float w10 = W0T[(cg1*2+1)*W0T_ROW + 0], w11 = W0T[(cg1*2+1)*W0T_ROW + 1];
        #pragma unroll
        for (int i = 0; i < 4; ++i) {
          const int b = bg1*4 + i;
          const float x0 = P.x[(long)b*(NT*2) + t*2 + 0];
          const float x1 = P.x[(long)b*(NT*2) + t*2 + 1];
          acc[i][0] += x0*w00 + x1*w01;
          acc[i][1] += x0*w10 + x1*w11;
        }
      }
      #pragma unroll 4
      for (int k = 0; k < NH; k += 4) {
        const float4 w0 = *(const float4*)&W0T[(cg1*2+0)*W0T_ROW + 4 + k];
        const float4 w1 = *(const float4*)&W0T[(cg1*2+1)*W0T_ROW + 4 + k];
        #pragma unroll
        for (int i = 0; i < 4; ++i) {
          const float4 a = *(const float4*)&hp[(long)(bg1*4+i)*NH + k];
          dot4(acc[i][0], a, w0);
          dot4(acc[i][1], a, w1);
        }
      }
      #pragma unroll
      for (int i = 0; i < 4; ++i) {
        gsm[(bg1*4+i)*17 + cg1*2 + 0] = acc[i][0];
        gsm[(bg1*4+i)*17 + cg1*2 + 1] = acc[i][1];
      }
      __syncthreads();
      {
        float* hnext = P.h0buf + (long)(((p+1)&1)*2 + dir)*65536;
        #pragma unroll
        for (int r = 0; r < 2; ++r) {
          const int pi2 = tid + r*256;
          const int b = pi2 >> 2, nl = pi2 & 3;
          const float iv = gsm[b*17 + 0  + nl];
          const float fv = gsm[b*17 + 4  + nl];
          const float gv = gsm[b*17 + 8  + nl];
          const float ov = gsm[b*17 + 12 + nl];
          float cold = r ? creg1 : creg0;
          const float cn = sigf(fv)*cold + sigf(iv)*tanhf(gv);
          const float hn = sigf(ov)*tanhf(cn);
          if (r) creg1 = cn; else creg0 = cn;
          stc_f(&hnext[(long)b*NH + n0 + nl], hn);        // coherent h
          P.y0[((long)t*NB + b)*1024 + dir*NH + n0 + nl] = __float2half_rn(hn);
        }
      }
      if (p < NT-1) { ++dstep; dir_arrive(dbar, dstep); dir_wait(dbar, dstep); }
      else          { full_arrive_f(fbar, 1); full_wait(fbar, 1); }  // transition
    }
    #pragma unroll
    for (int r = 0; r < 2; ++r) {
      const int pi2 = tid + r*256;
      P.c0fin[(long)dir*65536 + (long)(pi2>>2)*NH + n0 + (pi2&3)] = r ? creg1 : creg0;
    }
    creg0 = 0.f; creg1 = 0.f;
  }

  // phase 2: layer 1 (per-direction barriers, barrier-hidden pipeline)
  {
    const int bg2 = tid >> 2;
    const int cg2 = tid & 3;
    float accN[2][4], accC[2][4];
    {
      const int t0i = dir ? (NT-1) : 0;
      l1_ih_part(P.y0 + (long)t0i*NB*1024, W1T, bias1, bg2, cg2, accN);
    }
    for (int p = 0; p < NT; ++p) {
      const int t = dir ? (NT-1 - p) : p;
      #pragma unroll
      for (int i = 0; i < 2; ++i)
        #pragma unroll
        for (int j = 0; j < 4; ++j)
          accC[i][j] = accN[i][j];
      {
        const float* hp = P.h1buf + (long)((p&1)*2 + dir)*65536;
        const long r0 = (long)(bg2*2+0)*NH, r1 = (long)(bg2*2+1)*NH;
        #pragma unroll 4
        for (int k = 0; k < NH; k += 4) {
          const float4 w0 = *(const float4*)&W1T[(cg2*4+0)*W1T_ROW + 1024 + k];
          const float4 w1 = *(const float4*)&W1T[(cg2*4+1)*W1T_ROW + 1024 + k];
          const float4 w2 = *(const float4*)&W1T[(cg2*4+2)*W1T_ROW + 1024 + k];
          const float4 w3 = *(const float4*)&W1T[(cg2*4+3)*W1T_ROW + 1024 + k];
          const float4 a0 = *(const float4*)&hp[r0 + k];
          const float4 a1 = *(const float4*)&hp[r1 + k];
          dot4(accC[0][0], a0, w0); dot4(accC[0][1], a0, w1);
          dot4(accC[0][2], a0, w2); dot4(accC[0][3], a0, w3);
          dot4(accC[1][0], a1, w0); dot4(accC[1][1], a1, w1);
          dot4(accC[1][2], a1, w2); dot4(accC[1][3], a1, w3);
        }
      }
      #pragma unroll
      for (int i = 0; i < 2; ++i)
        #pragma unroll
        for (int j = 0; j < 4; ++j)
          gsm[(bg2*2+i)*17 + cg2*4 + j] = accC[i][j];
      __syncthreads();
      {
        float* hnext = P.h1buf + (long)(((p+1)&1)*2 + dir)*65536;
        #pragma unroll
        for (int r = 0; r < 2; ++r) {
          const int pi2 = tid + r*256;
          const int b = pi2 >> 2, nl = pi2 & 3;
          const float iv = gsm[b*17 + 0  + nl];
          const float fv = gsm[b*17 + 4  + nl];
          const float gv = gsm[b*17 + 8  + nl];
          const float ov = gsm[b*17 + 12 + nl];
          float cold = r ? creg1 : creg0;
          const float cn = sigf(fv)*cold + sigf(iv)*tanhf(gv);
          const float hn = sigf(ov)*tanhf(cn);
          if (r) creg1 = cn; else creg0 = cn;
          stc_f(&hnext[(long)b*NH + n0 + nl], hn);        // coherent h
          P.enc[((long)t*NB + b)*1024 + dir*NH + n0 + nl] = __float2half_rn(hn);
        }
      }
      if (p < NT-1) {
        ++dstep; dir_arrive(dbar, dstep);
        const int tn = dir ? (NT-1 - (p+1)) : (p+1);
        l1_ih_part(P.y0 + (long)tn*NB*1024, W1T, bias1, bg2, cg2, accN);
        dir_wait(dbar, dstep);
      }
    }
    #pragma unroll
    for (int r = 0; r < 2; ++r) {
      const int pi2 = tid + r*256;
      P.c1fin[(long)dir*65536 + (long)(pi2>>2)*NH + n0 + (pi2&3)] = r ? creg1 : creg0;
    }
  }
}

// ---------------------------------------------------------------------------
// Persistent cooperative decoder — FUSED per-row tail.
// Per step: stage1 L0 (blocks 0..127 by gate-cols) -> bar ->
//           stage2 L1 (blocks 128..255 by gate-cols) -> bar ->
//           stage3 FUSED query+attn+comb+logits+argmax (block b owns batch
//           row b, entire chain through LDS; blocks 128..255 idle) -> bar.
// 3 barriers/token (was 6). Weights for the fused chain stream from L2
// (row-coalesced); accumulation order matches the previous per-stage code
// exactly (bias first, k ascending in 4-chunks, grouped 4-term sums).
// ---------------------------------------------------------------------------
struct DecParams {
  const float* emb;
  const float* dWih; const float* dWhh; const float* dbv;
  const float* Wq;  const float* bq;
  const float* Wc;  const float* bc;
  const float* Wf;  const float* bf;
  const __half* enc;
  const float* h0e; const float* h1e;
  const float* c0fin; const float* c1fin;
  float* dh0; float* dh1;
  float* query; float* ctx; float* comb;   // unused in fused path (kept for fallback layout)
  int*   tok;
  float* dout;
  int*   bar;
};

#define WD_ROW 1026
#define DEC_LDS_FLOATS (16*WD_ROW + 16 + 128*17 + 1024 + 256 + 64 + 4 + 512 + 1024 + 128 + 128)
#define DEC_LDS_BYTES  (DEC_LDS_FLOATS*4)

__global__ __launch_bounds__(256, 1)
void decoder_kernel(DecParams P) {
  const int tid = threadIdx.x;
  const int lid = blockIdx.x;
  const int L   = lid >> 7;
  const int n0  = (lid & 127) * 4;
  int* bar = P.bar;

  extern __shared__ float lds[];
  float* WD    = lds;                  // 16*1026
  float* biasD = WD + 16*WD_ROW;       // 16
  float* gsm   = biasD + 16;           // 128*17
  float* qs    = gsm + 128*17;         // 1024 (query; later comb in [0..512))
  float* sc    = qs + 1024;            // 256
  float* ps    = sc + 256;             // 64
  float* m3    = ps + 64;              // 4
  float* cs    = m3 + 4;               // 512 (dec_out row)
  float* ctxs  = cs + 512;             // 1024 (context row)
  float* vals  = ctxs + 1024;          // 128
  int*   idxs  = (int*)(vals + 128);   // 128

  {
    const float* Wih = P.dWih + (long)L*512*NG;
    const float* Whh = P.dWhh + (long)L*512*NG;
    for (int e = tid; e < 16*1024; e += 256) {
      const int ci = e & 15, kk = e >> 4;
      const int gc = (ci>>2)*NH + n0 + (ci&3);
      WD[ci*WD_ROW + kk] = (kk < 512) ? Wih[(long)kk*NG + gc]
                                      : Whh[(long)(kk-512)*NG + gc];
    }
    if (tid < 16) biasD[tid] = P.dbv[(long)L*NG + (tid>>2)*NH + n0 + (tid&3)];
    const int i = lid*256 + tid;
    stc_f(&P.dh0[i], P.h0e[i] + P.h0e[65536 + i]);
    stc_f(&P.dh1[i], P.h1e[i] + P.h1e[65536 + i]);
    if (i < NB) stc_i(&P.tok[i], 1);
  }
  float cregA, cregB;
  {
    const float* cf = L ? P.c1fin : P.c0fin;
    const int b0i = tid >> 2, nl0 = tid & 3;
    cregA = cf[(long)b0i*NH + n0 + nl0] + cf[65536 + (long)b0i*NH + n0 + nl0];
    const int pi2 = tid + 256;
    const int b1i = pi2 >> 2, nl1 = pi2 & 3;
    cregB = cf[(long)b1i*NH + n0 + nl1] + cf[65536 + (long)b1i*NH + n0 + nl1];
  }
  int gstep = 0;
  ++gstep; full_arrive(bar, gstep); full_wait(bar, gstep);

  const int bg = tid >> 3;
  const int cg = tid & 7;

  for (int s = 0; s < NLW; ++s) {
    float* dh0c = P.dh0 + (s&1)*65536;
    float* dh0n = P.dh0 + ((s+1)&1)*65536;
    float* dh1c = P.dh1 + (s&1)*65536;
    float* dh1n = P.dh1 + ((s+1)&1)*65536;

    // ---------- stage 1: decoder LSTM layer 0 (blocks 0..127) ----------
    if (L == 0) {
      float acc[4][2];
      #pragma unroll
      for (int i = 0; i < 4; ++i) { acc[i][0] = biasD[cg*2]; acc[i][1] = biasD[cg*2+1]; }
      int rows[4];
      #pragma unroll
      for (int i = 0; i < 4; ++i) rows[i] = P.tok[bg*4 + i];
      #pragma unroll 4
      for (int k = 0; k < NH; k += 4) {
        const float4 w0 = *(const float4*)&WD[(cg*2+0)*WD_ROW + k];
        const float4 w1 = *(const float4*)&WD[(cg*2+1)*WD_ROW + k];
        #pragma unroll
        for (int i = 0; i < 4; ++i) {
          const float4 a = *(const float4*)&P.emb[(long)rows[i]*NH + k];
          dot4(acc[i][0], a, w0);
          dot4(acc[i][1], a, w1);
        }
      }
      #pragma unroll 4
      for (int k = 0; k < NH; k += 4) {
        const float4 w0 = *(const float4*)&WD[(cg*2+0)*WD_ROW + 512 + k];
        const float4 w1 = *(const float4*)&WD[(cg*2+1)*WD_ROW + 512 + k];
        #pragma unroll
        for (int i = 0; i < 4; ++i) {
          const float4 a = *(const float4*)&dh0c[(long)(bg*4+i)*NH + k];
          dot4(acc[i][0], a, w0);
          dot4(acc[i][1], a, w1);
        }
      }
      #pragma unroll
      for (int i = 0; i < 4; ++i) {
        gsm[(bg*4+i)*17 + cg*2 + 0] = acc[i][0];
        gsm[(bg*4+i)*17 + cg*2 + 1] = acc[i][1];
      }
      __syncthreads();
      #pragma unroll
      for (int r = 0; r < 2; ++r) {
        const int pi2 = tid + r*256;
        const int b = pi2 >> 2, nl = pi2 & 3;
        const float iv = gsm[b*17 + 0  + nl];
        const float fv = gsm[b*17 + 4  + nl];
        const float gv = gsm[b*17 + 8  + nl];
        const float ov = gsm[b*17 + 12 + nl];
        const float cold = r ? cregB : cregA;
        const float cn = sigf(fv)*cold + sigf(iv)*tanhf(gv);
        const float hn = sigf(ov)*tanhf(cn);
        if (r) cregB = cn; else cregA = cn;
        stc_f(&dh0n[(long)b*NH + n0 + nl], hn);
      }
    }
    ++gstep; full_arrive(bar, gstep); full_wait(bar, gstep);

    // ---------- stage 2: decoder LSTM layer 1 (blocks 128..255) ----------
    if (L == 1) {
      float acc[4][2];
      #pragma unroll
      for (int i = 0; i < 4; ++i) { acc[i][0] = biasD[cg*2]; acc[i][1] = biasD[cg*2+1]; }
      #pragma unroll 4
      for (int k = 0; k < NH; k += 4) {
        const float4 w0 = *(const float4*)&WD[(cg*2+0)*WD_ROW + k];
        const float4 w1 = *(const float4*)&WD[(cg*2+1)*WD_ROW + k];
        #pragma unroll
        for (int i = 0; i < 4; ++i) {
          const float4 a = *(const float4*)&dh0n[(long)(bg*4+i)*NH + k];
          dot4(acc[i][0], a, w0);
          dot4(acc[i][1], a, w1);
        }
      }
      #pragma unroll 4
      for (int k = 0; k < NH; k += 4) {
        const float4 w0 = *(const float4*)&WD[(cg*2+0)*WD_ROW + 512 + k];
        const float4 w1 = *(const float4*)&WD[(cg*2+1)*WD_ROW + 512 + k];
        #pragma unroll
        for (int i = 0; i < 4; ++i) {
          const float4 a = *(const float4*)&dh1c[(long)(bg*4+i)*NH + k];
          dot4(acc[i][0], a, w0);
          dot4(acc[i][1], a, w1);
        }
      }
      #pragma unroll
      for (int i = 0; i < 4; ++i) {
        gsm[(bg*4+i)*17 + cg*2 + 0] = acc[i][0];
        gsm[(bg*4+i)*17 + cg*2 + 1] = acc[i][1];
      }
      __syncthreads();
      #pragma unroll
      for (int r = 0; r < 2; ++r) {
        const int pi2 = tid + r*256;
        const int b = pi2 >> 2, nl = pi2 & 3;
        const float iv = gsm[b*17 + 0  + nl];
        const float fv = gsm[b*17 + 4  + nl];
        const float gv = gsm[b*17 + 8  + nl];
        const float ov = gsm[b*17 + 12 + nl];
        const float cold = r ? cregB : cregA;
        const float cn = sigf(fv)*cold + sigf(iv)*tanhf(gv);
        const float hn = sigf(ov)*tanhf(cn);
        if (r) cregB = cn; else cregA = cn;
        stc_f(&dh1n[(long)b*NH + n0 + nl], hn);
      }
    }
    ++gstep; full_arrive(bar, gstep); full_wait(bar, gstep);

    // ---------- stage 3 (FUSED): query+attn+comb+logits+argmax, row b ----
    if (lid < NB) {
      const int b = lid;
      for (int i = tid; i < NH; i += 256) cs[i] = dh1n[(long)b*NH + i];
      if (tid == 0) { m3[0] = -1e30f; m3[1] = 0.f; m3[2] = 0.f; }
      __syncthreads();
      // query[b][tid*4..+4] = bias + dec_out @ Wq  (k asc, 4-chunks)
      {
        const int jc = tid*4;
        float4 a4 = *(const float4*)&P.bq[jc];
        for (int k = 0; k < NH; k += 4) {
          const float h0 = cs[k], h1 = cs[k+1], h2 = cs[k+2], h3 = cs[k+3];
          const float4 r0 = *(const float4*)&P.Wq[(long)(k+0)*1024 + jc];
          const float4 r1 = *(const float4*)&P.Wq[(long)(k+1)*1024 + jc];
          const float4 r2 = *(const float4*)&P.Wq[(long)(k+2)*1024 + jc];
          const float4 r3 = *(const float4*)&P.Wq[(long)(k+3)*1024 + jc];
          a4.x += h0*r0.x + h1*r1.x + h2*r2.x + h3*r3.x;
          a4.y += h0*r0.y + h1*r1.y + h2*r2.y + h3*r3.y;
          a4.z += h0*r0.z + h1*r1.z + h2*r2.z + h3*r3.z;
          a4.w += h0*r0.w + h1*r1.w + h2*r2.w + h3*r3.w;
        }
        *(float4*)&qs[jc] = a4;
      }
      __syncthreads();
      // attention over enc[t][b][:] (verbatim structure)
      float4 ctx4 = {0,0,0,0};
      for (int c = 0; c < 4; ++c) {
        const int t0 = c*64;
        {
          const int t_l = tid >> 2, part = tid & 3;
          const __half* er = P.enc + ((long)(t0 + t_l)*NB + b)*1024 + part*256;
          const float* qr = qs + part*256;
          float sv = 0.f;
          for (int k = 0; k < 256; k += 4) {
            const float4 e4 = ldh4(er + k);
            const float4 q4 = *(const float4*)(qr + k);
            sv += e4.x*q4.x + e4.y*q4.y + e4.z*q4.z + e4.w*q4.w;
          }
          sv += __shfl_xor(sv, 1);
          sv += __shfl_xor(sv, 2);
          if (part == 0) sc[t0 + t_l] = sv;
        }
        __syncthreads();
        if (tid < 64) {
          float sv = sc[t0 + tid];
          for (int off = 32; off; off >>= 1) sv = fmaxf(sv, __shfl_xor(sv, off));
          if (tid == 0) {
            const float mn = fmaxf(m3[0], sv);
            m3[2] = expf(m3[0] - mn);
            m3[0] = mn;
          }
        }
        __syncthreads();
        const float alpha = m3[2];
        if (tid < 64) {
          float pv = expf(sc[t0 + tid] - m3[0]);
          ps[tid] = pv;
          for (int off = 32; off; off >>= 1) pv += __shfl_xor(pv, off);
          if (tid == 0) m3[1] = m3[1]*alpha + pv;
        }
        __syncthreads();
        ctx4.x *= alpha; ctx4.y *= alpha; ctx4.z *= alpha; ctx4.w *= alpha;
        const __half* ecol = P.enc + ((long)t0*NB + b)*1024 + tid*4;
        for (int t = 0; t < 64; ++t) {
          const float4 e4 = ldh4(ecol + (long)t*(NB*1024));
          fma4(ctx4, ps[t], e4);
        }
        __syncthreads();
      }
      const float linv = 1.0f / m3[1];
      ctxs[tid*4+0] = ctx4.x*linv; ctxs[tid*4+1] = ctx4.y*linv;
      ctxs[tid*4+2] = ctx4.z*linv; ctxs[tid*4+3] = ctx4.w*linv;
      const float pv = expf(sc[tid] - m3[0]) * linv;
      P.dout[786432L + (long)b*(NT*NLW) + (long)tid*NLW + s] = pv;
      __syncthreads();
      // comb[b][tid*2..+2] = bias + [dec_out, ctx] @ Wc  (k asc, 4-chunks)
      {
        const int c2 = tid*2;
        float ax = P.bc[c2 + 0], ay = P.bc[c2 + 1];
        for (int k = 0; k < NH; k += 4) {
          const float h0 = cs[k], h1 = cs[k+1], h2 = cs[k+2], h3 = cs[k+3];
          const float2 r0 = *(const float2*)&P.Wc[(long)(k+0)*NH + c2];
          const float2 r1 = *(const float2*)&P.Wc[(long)(k+1)*NH + c2];
          const float2 r2 = *(const float2*)&P.Wc[(long)(k+2)*NH + c2];
          const float2 r3 = *(const float2*)&P.Wc[(long)(k+3)*NH + c2];
          ax += h0*r0.x + h1*r1.x + h2*r2.x + h3*r3.x;
          ay += h0*r0.y + h1*r1.y + h2*r2.y + h3*r3.y;
        }
        for (int k = 0; k < 1024; k += 4) {
          const float h0 = ctxs[k], h1 = ctxs[k+1], h2 = ctxs[k+2], h3 = ctxs[k+3];
          const float2 r0 = *(const float2*)&P.Wc[(long)(512+k+0)*NH + c2];
          const float2 r1 = *(const float2*)&P.Wc[(long)(512+k+1)*NH + c2];
          const float2 r2 = *(const float2*)&P.Wc[(long)(512+k+2)*NH + c2];
          const float2 r3 = *(const float2*)&P.Wc[(long)(512+k+3)*NH + c2];
          ax += h0*r0.x + h1*r1.x + h2*r2.x + h3*r3.x;
          ay += h0*r0.y + h1*r1.y + h2*r2.y + h3*r3.y;
        }
        __syncthreads();          // qs (query) dead; reuse qs[0..512) for comb
        qs[c2 + 0] = ax;
        qs[c2 + 1] = ay;
      }
      __syncthreads();
      // logits + argmax (threads 0..127), reading comb from qs
      if (tid < NV) {
        float acc = P.bf[tid];
        for (int k = 0; k < NH; k += 4) {
          const float4 c4 = *(const float4*)&qs[k];
          acc += c4.x*P.Wf[(long)(k+0)*NV + tid];
          acc += c4.y*P.Wf[(long)(k+1)*NV + tid];
          acc += c4.z*P.Wf[(long)(k+2)*NV + tid];
          acc += c4.w*P.Wf[(long)(k+3)*NV + tid];
        }
        P.dout[(long)b*(NLW*NV) + (long)s*NV + tid] = acc;
        vals[tid] = acc; idxs[tid] = tid;
      }
      __syncthreads();
      for (int st2 = 64; st2 > 0; st2 >>= 1) {
        if (tid < st2) {
          const float v2 = vals[tid+st2]; const int i2 = idxs[tid+st2];
          if (v2 > vals[tid] || (v2 == vals[tid] && i2 < idxs[tid])) { vals[tid] = v2; idxs[tid] = i2; }
        }
        __syncthreads();
      }
      if (tid == 0) stc_i(&P.tok[b], idxs[0]);
    }
    ++gstep; full_arrive(bar, gstep); full_wait(bar, gstep);
  }

  {
    const int i = lid*256 + tid;
    P.dout[524288L + i]         = P.dh0[i];
    P.dout[524288L + 65536 + i] = P.dh1[i];
    #pragma unroll
    for (int r = 0; r < 2; ++r) {
      const int pi2 = tid + r*256;
      const int b = pi2 >> 2, nl = pi2 & 3;
      P.dout[655360L + (long)L*65536 + (long)b*NH + n0 + nl] = r ? cregB : cregA;
    }
  }
}

// ---------------------------------------------------------------------------
// Fused LSTM gate-GEMM + cell update (fallback paths).
// ---------------------------------------------------------------------------
struct StepDir {
  const void*  A;
  const float* WA;
  const float* Bs;
  const float* WB;
  const float* x2;
  const float* Wx;
  const int*   rowIdxA;
  const float* bias;
  float*  c_io;
  float*  h_out;
  __half* yh_out;
  int sA, KA, sB, KB, sx2, ystride, aHalf;
};
struct StepParams { StepDir d[2]; };

__global__ __launch_bounds__(256)
void lstm_step_kernel(StepParams P) {
  const StepDir p = P.d[blockIdx.z];
  const int tid = threadIdx.x;
  const int nq  = tid & 3;
  const int g   = (tid >> 2) & 3;
  const int bp  = tid >> 4;
  const int bl0 = bp*2;
  const int b0  = blockIdx.y*32 + bl0;
  const int n0  = blockIdx.x*16 + nq*4;
  const int gc  = g*NH + n0;

  float4 acc0 = *(const float4*)(p.bias + gc);
  float4 acc1 = acc0;

  if (p.x2) {
    const float4 w0 = *(const float4*)(p.Wx + gc);
    const float4 w1 = *(const float4*)(p.Wx + NG + gc);
    const float* xr0 = p.x2 + (long)b0     * p.sx2;
    const float* xr1 = p.x2 + (long)(b0+1) * p.sx2;
    fma4(acc0, xr0[0], w0); fma4(acc0, xr0[1], w1);
    fma4(acc1, xr1[0], w0); fma4(acc1, xr1[1], w1);
  }
  if (p.KA > 0) {
    const int r0 = p.rowIdxA ? p.rowIdxA[b0]   : b0;
    const int r1 = p.rowIdxA ? p.rowIdxA[b0+1] : b0+1;
    const float* Wp = p.WA + gc;
    if (p.aHalf) {
      const __half* rA0 = (const __half*)p.A + (long)r0 * p.sA;
      const __half* rA1 = (const __half*)p.A + (long)r1 * p.sA;
      for (int k = 0; k < p.KA; k += 4) {
        const float4 a0 = ldh4(rA0 + k);
        const float4 a1 = ldh4(rA1 + k);
        const float4 w0 = *(const float4*)(Wp + (long)(k+0)*NG);
        const float4 w1 = *(const float4*)(Wp + (long)(k+1)*NG);
        const float4 w2 = *(const float4*)(Wp + (long)(k+2)*NG);
        const float4 w3 = *(const float4*)(Wp + (long)(k+3)*NG);
        fma4(acc0, a0.x, w0); fma4(acc0, a0.y, w1); fma4(acc0, a0.z, w2); fma4(acc0, a0.w, w3);
        fma4(acc1, a1.x, w0); fma4(acc1, a1.y, w1); fma4(acc1, a1.z, w2); fma4(acc1, a1.w, w3);
      }
    } else {
      const float* rA0 = (const float*)p.A + (long)r0 * p.sA;
      const float* rA1 = (const float*)p.A + (long)r1 * p.sA;
      for (int k = 0; k < p.KA; k += 4) {
        const float4 a0 = *(const float4*)(rA0 + k);
        const float4 a1 = *(const float4*)(rA1 + k);
        const float4 w0 = *(const float4*)(Wp + (long)(k+0)*NG);
        const float4 w1 = *(const float4*)(Wp + (long)(k+1)*NG);
        const float4 w2 = *(const float4*)(Wp + (long)(k+2)*NG);
        const float4 w3 = *(const float4*)(Wp + (long)(k+3)*NG);
        fma4(acc0, a0.x, w0); fma4(acc0, a0.y, w1); fma4(acc0, a0.z, w2); fma4(acc0, a0.w, w3);
        fma4(acc1, a1.x, w0); fma4(acc1, a1.y, w1); fma4(acc1, a1.z, w2); fma4(acc1, a1.w, w3);
      }
    }
  }
  {
    const float* rB0 = p.Bs + (long)b0     * p.sB;
    const float* rB1 = p.Bs + (long)(b0+1) * p.sB;
    const float* Wp = p.WB + gc;
    for (int k = 0; k < p.KB; k += 4) {
      const float4 a0 = *(const float4*)(rB0 + k);
      const float4 a1 = *(const float4*)(rB1 + k);
      const float4 w0 = *(const float4*)(Wp + (long)(k+0)*NG);
      const float4 w1 = *(const float4*)(Wp + (long)(k+1)*NG);
      const float4 w2 = *(const float4*)(Wp + (long)(k+2)*NG);
      const float4 w3 = *(const float4*)(Wp + (long)(k+3)*NG);
      fma4(acc0, a0.x, w0); fma4(acc0, a0.y, w1); fma4(acc0, a0.z, w2); fma4(acc0, a0.w, w3);
      fma4(acc1, a1.x, w0); fma4(acc1, a1.y, w1); fma4(acc1, a1.z, w2); fma4(acc1, a1.w, w3);
    }
  }

  __shared__ __align__(16) float gs[32][68];
  {
    float* r0 = &gs[bl0][g*17 + nq*4];
    r0[0]=acc0.x; r0[1]=acc0.y; r0[2]=acc0.z; r0[3]=acc0.w;
    float* r1 = &gs[bl0+1][g*17 + nq*4];
    r1[0]=acc1.x; r1[1]=acc1.y; r1[2]=acc1.z; r1[3]=acc1.w;
  }
  __syncthreads();
  for (int pi = tid; pi < 512; pi += 256) {
    const int b_l = pi >> 4, n_l = pi & 15;
    const float iv = gs[b_l][0*17 + n_l];
    const float fv = gs[b_l][1*17 + n_l];
    const float gv = gs[b_l][2*17 + n_l];
    const float ov = gs[b_l][3*17 + n_l];
    const int bg = blockIdx.y*32 + b_l;
    const long idx = (long)bg*NH + blockIdx.x*16 + n_l;
    const float c_old = p.c_io[idx];
    const float cn = sigf(fv)*c_old + sigf(iv)*tanhf(gv);
    const float hn = sigf(ov)*tanhf(cn);
    p.c_io[idx]  = cn;
    p.h_out[idx] = hn;
    if (p.yh_out)
      p.yh_out[(long)bg*p.ystride + blockIdx.x*16 + n_l] = __float2half_rn(hn);
  }
}

// ---------------------------------------------------------------------------
struct LinParams {
  const float* A; const float* Bs; const float* W; const float* bias;
  float* out;
  int sA, KA, sB, KB, N;
};

__global__ __launch_bounds__(256)
void linear2_kernel(LinParams p) {
  __shared__ __align__(16) float As[64][36];
  const int tid = threadIdx.x;
  const int jl = tid & 63;
  const int j = blockIdx.x*64 + jl;
  const int bo = (tid >> 6)*8;
  const int bbase = blockIdx.y*32;
  float acc[8] = {0,0,0,0,0,0,0,0};
  for (int src = 0; src < 2; ++src) {
    const float* A = src ? p.Bs : p.A;
    const int sA   = src ? p.sB : p.sA;
    const int K    = src ? p.KB : p.KA;
    const float* W = src ? (p.W + (long)p.KA*p.N) : p.W;
    if (!A || K <= 0) continue;
    for (int k0 = 0; k0 < K; k0 += 64) {
      __syncthreads();
      for (int e = tid; e < 32*64; e += 256) {
        const int bl = e >> 6, kk = e & 63;
        As[kk][bl] = A[(long)(bbase+bl)*sA + k0 + kk];
      }
      __syncthreads();
      const float* Wp = W + (long)k0*p.N + j;
      for (int k = 0; k < 64; ++k) {
        const float wv = Wp[(long)k*p.N];
        const float4 aA = *(const float4*)&As[k][bo];
        const float4 aB = *(const float4*)&As[k][bo+4];
        acc[0] += aA.x*wv; acc[1] += aA.y*wv; acc[2] += aA.z*wv; acc[3] += aA.w*wv;
        acc[4] += aB.x*wv; acc[5] += aB.y*wv; acc[6] += aB.z*wv; acc[7] += aB.w*wv;
      }
    }
  }
  const float bv = p.bias ? p.bias[j] : 0.f;
  for (int i = 0; i < 8; ++i)
    p.out[(long)(bbase + bo + i)*p.N + j] = acc[i] + bv;
}

// ---------------------------------------------------------------------------
__global__ __launch_bounds__(256)
void attn_kernel(const float* __restrict__ query, const __half* __restrict__ enc,
                 float* __restrict__ context, float* __restrict__ attn_out, int step) {
  const int b = blockIdx.x;
  const int tid = threadIdx.x;
  __shared__ __align__(16) float qs[1024];
  __shared__ float sc[256];
  __shared__ float ps[64];
  __shared__ float msh, lsh, ash;
  for (int i = tid; i < 1024; i += 256) qs[i] = query[(long)b*1024 + i];
  if (tid == 0) { msh = -1e30f; lsh = 0.f; ash = 0.f; }
  __syncthreads();
  float4 ctx = {0,0,0,0};
  for (int c = 0; c < 4; ++c) {
    const int t0 = c*64;
    {
      const int t_l = tid >> 2, part = tid & 3;
      const __half* er = enc + ((long)(t0 + t_l)*NB + b)*1024 + part*256;
      const float* qr = qs + part*256;
      float sv = 0.f;
      for (int k = 0; k < 256; k += 4) {
        const float4 e4 = ldh4(er + k);
        const float4 q4 = *(const float4*)(qr + k);
        sv += e4.x*q4.x + e4.y*q4.y + e4.z*q4.z + e4.w*q4.w;
      }
      sv += __shfl_xor(sv, 1);
      sv += __shfl_xor(sv, 2);
      if (part == 0) sc[t0 + t_l] = sv;
    }
    __syncthreads();
    if (tid < 64) {
      float sv = sc[t0 + tid];
      for (int off = 32; off; off >>= 1) sv = fmaxf(sv, __shfl_xor(sv, off));
      if (tid == 0) {
        const float mn = fmaxf(msh, sv);
        ash = expf(msh - mn);
        msh = mn;
      }
    }
    __syncthreads();
    const float alpha = ash;
    if (tid < 64) {
      float pv = expf(sc[t0 + tid] - msh);
      ps[tid] = pv;
      for (int off = 32; off; off >>= 1) pv += __shfl_xor(pv, off);
      if (tid == 0) lsh = lsh*alpha + pv;
    }
    __syncthreads();
    ctx.x *= alpha; ctx.y *= alpha; ctx.z *= alpha; ctx.w *= alpha;
    const __half* ecol = enc + ((long)t0*NB + b)*1024 + tid*4;
    for (int t = 0; t < 64; ++t) {
      const float4 e4 = ldh4(ecol + (long)t*(NB*1024));
      fma4(ctx, ps[t], e4);
    }
    __syncthreads();
  }
  const float linv = 1.0f / lsh;
  const long cb = (long)b*1024 + tid*4;
  context[cb+0] = ctx.x*linv; context[cb+1] = ctx.y*linv;
  context[cb+2] = ctx.z*linv; context[cb+3] = ctx.w*linv;
  const float pv = expf(sc[tid] - msh) * linv;
  attn_out[(long)b*(NT*NLW) + (long)tid*NLW + step] = pv;
}

// ---------------------------------------------------------------------------
__global__ __launch_bounds__(128)
void logits_kernel(const float* __restrict__ comb, const float* __restrict__ Wf,
                   const float* __restrict__ bfv, float* __restrict__ out,
                   int sOut, int* __restrict__ tok) {
  const int b = blockIdx.x;
  const int v = threadIdx.x;
  __shared__ __align__(16) float cs[512];
  __shared__ float vals[128];
  __shared__ int idxs[128];
  for (int i = v; i < 512; i += 128) cs[i] = comb[(long)b*512 + i];
  __syncthreads();
  float acc = bfv[v];
  for (int k = 0; k < 512; k += 4) {
    const float4 c4 = *(const float4*)&cs[k];
    acc += c4.x*Wf[(long)(k+0)*NV + v];
    acc += c4.y*Wf[(long)(k+1)*NV + v];
    acc += c4.z*Wf[(long)(k+2)*NV + v];
    acc += c4.w*Wf[(long)(k+3)*NV + v];
  }
  out[(long)b*sOut + v] = acc;
  vals[v] = acc; idxs[v] = v;
  __syncthreads();
  for (int s = 64; s > 0; s >>= 1) {
    if (v < s) {
      const float v2 = vals[v+s]; const int i2 = idxs[v+s];
      if (v2 > vals[v] || (v2 == vals[v] && i2 < idxs[v])) { vals[v] = v2; idxs[v] = i2; }
    }
    __syncthreads();
  }
  if (v == 0) tok[b] = idxs[0];
}

// ---------------------------------------------------------------------------
__global__ void init_dec_kernel(const float* h00, const float* h01,
                                const float* c00, const float* c01,
                                const float* h10, const float* h11,
                                const float* c10, const float* c11,
                                float* dh0, float* dh1, float* dc0, float* dc1,
                                int* tok) {
  const int i = blockIdx.x*256 + threadIdx.x;
  dh0[i] = h00[i] + h01[i];
  dc0[i] = c00[i] + c01[i];
  dh1[i] = h10[i] + h11[i];
  dc1[i] = c10[i] + c11[i];
  if (i < NB) tok[i] = 1;
}

__global__ void final_copy_kernel(const float* dh0, const float* dh1,
                                  const float* dc0, const float* dc1,
                                  float* out_h, float* out_c) {
  const int i = blockIdx.x*256 + threadIdx.x;
  out_h[i] = dh0[i]; out_h[65536 + i] = dh1[i];
  out_c[i] = dc0[i]; out_c[65536 + i] = dc1[i];
}

// ---------------------------------------------------------------------------
extern "C" void kernel_launch(void* const* d_in, const int* in_sizes, int n_in,
                              void* d_out_v, int out_size, void* d_ws, size_t ws_size,
                              hipStream_t stream) {
  (void)in_sizes; (void)n_in; (void)out_size;
  const float* x    = (const float*)d_in[0];
  const float* W0ih = (const float*)d_in[1];
  const float* W0hh = (const float*)d_in[2];
  const float* b0v  = (const float*)d_in[3];
  const float* W1ih = (const float*)d_in[4];
  const float* W1hh = (const float*)d_in[5];
  const float* b1v  = (const float*)d_in[6];
  const float* dWih = (const float*)d_in[7];
  const float* dWhh = (const float*)d_in[8];
  const float* dbv  = (const float*)d_in[9];
  const float* emb  = (const float*)d_in[10];
  const float* Wq   = (const float*)d_in[11];
  const float* bq   = (const float*)d_in[12];
  const float* Wc   = (const float*)d_in[13];
  const float* bc   = (const float*)d_in[14];
  const float* Wf   = (const float*)d_in[15];
  const float* bfv  = (const float*)d_in[16];

  // ---- workspace layout (float slots) ----
  const long Y0_SLOTS  = 16777216L;
  const long ENC_SLOTS = 16777216L;
  const long BAR_SLOTS = 40960L;
  const long ST_SZ     = 786432L + BAR_SLOTS;
  const long DEC_SZ    = 655488L;
  const long NEEDED    = Y0_SLOTS + ENC_SLOTS + ST_SZ + DEC_SZ;
  if (ws_size < (size_t)NEEDED*4) return;

  float*  ws    = (float*)d_ws;
  __half* y0h   = (__half*)ws;
  __half* ench  = (__half*)(ws + Y0_SLOTS);
  float*  st    = ws + Y0_SLOTS + ENC_SLOTS;
  float*  h0buf = st;
  float*  h1buf = st + 262144;
  float*  c0fin = st + 524288;
  float*  c1fin = st + 655360;
  int*    barE  = (int*)(st + 786432);       // 26624 ints used
  int*    barD  = barE + 28672;              // decoder full barrier
  float*  dec   = st + ST_SZ;
  float* ddh0  = dec + 0;
  float* ddh1  = dec + 131072;
  float* dcomb = dec + 262144;
  float* query = dec + 393216;
  float* ctx   = dec + 524288;
  int*   tok   = (int*)(dec + 655360);
  float* dh[2][2] = {{dec+0, dec+65536}, {dec+131072, dec+196608}};
  float* dc[2]    =  {dec+262144, dec+327680};
  float* comb  = query;
  float* dout  = (float*)d_out_v;

  hipMemsetAsync(st, 0, ST_SZ*4, stream);

  EncParams EP;
  EP.x = x; EP.W0ih = W0ih; EP.W0hh = W0hh; EP.b0 = b0v;
  EP.W1ih = W1ih; EP.W1hh = W1hh; EP.b1 = b1v;
  EP.y0 = y0h; EP.enc = ench;
  EP.h0buf = h0buf; EP.h1buf = h1buf; EP.c0fin = c0fin; EP.c1fin = c1fin;
  EP.bar = barE;

  static int attrDone = 0;
  if (!attrDone) {
    (void)hipFuncSetAttribute(reinterpret_cast<const void*>(encoder_kernel),
                              hipFuncAttributeMaxDynamicSharedMemorySize,
                              ENC_LDS_BYTES);
    (void)hipFuncSetAttribute(reinterpret_cast<const void*>(decoder_kernel),
                              hipFuncAttributeMaxDynamicSharedMemorySize,
                              DEC_LDS_BYTES);
    attrDone = 1;
  }
  void* eargs[] = { (void*)&EP };
  hipError_t cerr = hipLaunchCooperativeKernel(
      reinterpret_cast<const void*>(encoder_kernel),
      dim3(256), dim3(256), eargs, (unsigned int)ENC_LDS_BYTES, stream);

  if (cerr != hipSuccess) {
    for (int p = 0; p < NT; ++p) {
      StepParams SP{};
      for (int d = 0; d < 2; ++d) {
        const int t = d ? (NT-1-p) : p;
        StepDir& q = SP.d[d];
        q.A = nullptr; q.WA = nullptr; q.sA = 0; q.KA = 0; q.aHalf = 0;
        q.Bs = h0buf + (long)((p&1)*2 + d)*65536; q.sB = NH; q.KB = NH;
        q.WB = W0hh + (long)d*NH*NG;
        q.x2 = x + (long)t*2; q.sx2 = NT*2; q.Wx = W0ih + (long)d*2*NG;
        q.rowIdxA = nullptr; q.bias = b0v + (long)d*NG;
        q.c_io = c0fin + (long)d*65536;
        q.h_out = h0buf + (long)(((p+1)&1)*2 + d)*65536;
        q.yh_out = y0h + (long)t*(NB*1024) + d*NH; q.ystride = 1024;
      }
      lstm_step_kernel<<<dim3(32,4,2), 256, 0, stream>>>(SP);
    }
    for (int p = 0; p < NT; ++p) {
      StepParams SP{};
      for (int d = 0; d < 2; ++d) {
        const int t = d ? (NT-1-p) : p;
        StepDir& q = SP.d[d];
        q.A = y0h + (long)t*(NB*1024); q.aHalf = 1; q.sA = 1024; q.KA = 2*NH;
        q.WA = W1ih + (long)d*(2*NH)*NG;
        q.Bs = h1buf + (long)((p&1)*2 + d)*65536; q.sB = NH; q.KB = NH;
        q.WB = W1hh + (long)d*NH*NG;
        q.x2 = nullptr; q.sx2 = 0; q.Wx = nullptr;
        q.rowIdxA = nullptr; q.bias = b1v + (long)d*NG;
        q.c_io = c1fin + (long)d*65536;
        q.h_out = h1buf + (long)(((p+1)&1)*2 + d)*65536;
        q.yh_out = ench + (long)t*(NB*1024) + d*NH; q.ystride = 1024;
      }
      lstm_step_kernel<<<dim3(32,4,2), 256, 0, stream>>>(SP);
    }
  }

  DecParams DP;
  DP.emb = emb; DP.dWih = dWih; DP.dWhh = dWhh; DP.dbv = dbv;
  DP.Wq = Wq; DP.bq = bq; DP.Wc = Wc; DP.bc = bc; DP.Wf = Wf; DP.bf = bfv;
  DP.enc = ench;
  DP.h0e = h0buf; DP.h1e = h1buf;
  DP.c0fin = c0fin; DP.c1fin = c1fin;
  DP.dh0 = ddh0; DP.dh1 = ddh1;
  DP.query = query; DP.ctx = ctx; DP.comb = dcomb;
  DP.tok = tok; DP.dout = dout; DP.bar = barD;

  void* dargs[] = { (void*)&DP };
  hipError_t derr = hipLaunchCooperativeKernel(
      reinterpret_cast<const void*>(decoder_kernel),
      dim3(256), dim3(256), dargs, (unsigned int)DEC_LDS_BYTES, stream);

  if (derr != hipSuccess) {
    init_dec_kernel<<<256, 256, 0, stream>>>(h0buf, h0buf+65536, c0fin, c0fin+65536,
                                             h1buf, h1buf+65536, c1fin, c1fin+65536,
                                             dh[0][0], dh[1][0], dc[0], dc[1], tok);
    for (int s = 0; s < NLW; ++s) {
      const int si = s&1, so = (s+1)&1;
      {
        StepParams SP{};
        StepDir& q = SP.d[0];
        q.A = emb; q.sA = NH; q.KA = NH; q.aHalf = 0; q.WA = dWih;
        q.Bs = dh[0][si]; q.sB = NH; q.KB = NH; q.WB = dWhh;
        q.x2 = nullptr; q.sx2 = 0; q.Wx = nullptr;
        q.rowIdxA = tok;
        q.bias = dbv;
        q.c_io = dc[0]; q.h_out = dh[0][so];
        q.yh_out = nullptr; q.ystride = 0;
        lstm_step_kernel<<<dim3(32,4,1), 256, 0, stream>>>(SP);
      }
      {
        StepParams SP{};
        StepDir& q = SP.d[0];
        q.A = dh[0][so]; q.sA = NH; q.KA = NH; q.aHalf = 0; q.WA = dWih + (long)NH*NG;
        q.Bs = dh[1][si]; q.sB = NH; q.KB = NH; q.WB = dWhh + (long)NH*NG;
        q.x2 = nullptr; q.sx2 = 0; q.Wx = nullptr;
        q.rowIdxA = nullptr;
        q.bias = dbv + NG;
        q.c_io = dc[1]; q.h_out = dh[1][so];
        q.yh_out = nullptr; q.ystride = 0;
        lstm_step_kernel<<<dim3(32,4,1), 256, 0, stream>>>(SP);
      }
      {
        LinParams LP{ dh[1][so], nullptr, Wq, bq, query, NH, NH, 0, 0, 2*NH };
        linear2_kernel<<<dim3(16,4), 256, 0, stream>>>(LP);
      }
      attn_kernel<<<128, 256, 0, stream>>>(query, ench, ctx, dout + 786432L, s);
      {
        LinParams LP{ dh[1][so], ctx, Wc, bc, comb, NH, NH, 2*NH, 2*NH, NH };
        linear2_kernel<<<dim3(8,4), 256, 0, stream>>>(LP);
      }
      logits_kernel<<<128, 128, 0, stream>>>(comb, Wf, bfv, dout + (long)s*NV,
                                             NLW*NV, tok);
    }
    final_copy_kernel<<<256, 256, 0, stream>>>(dh[0][0], dh[1][0], dc[0], dc[1],
                                               dout + 524288L, dout + 655360L);
  }
}